// Round 1
// baseline (14696.227 us; speedup 1.0000x reference)
//
#include <hip/hip_runtime.h>

// Problem constants
constexpr int TT = 1000;
constexpr int ST = 20;   // padded LDS stride (rows 16B-aligned, odd-ish banks)

// d_out layout (floats): z | kl | EXXT | EX | EXXNT
constexpr long long Z_OFF     = 0;
constexpr long long KL_OFF    = 1024000;
constexpr long long EXXT_OFF  = 1024064;
constexpr long long EX_OFF    = 17408064;
constexpr long long EXXNT_OFF = 18432064;

// ---------- small helpers ----------
__device__ __forceinline__ float red16(float v){
  v += __shfl_xor(v, 1);
  v += __shfl_xor(v, 2);
  v += __shfl_xor(v, 4);
  v += __shfl_xor(v, 8);
  return v;  // sum over the 16-lane group (threads sharing i); all lanes get it
}

__device__ __forceinline__ float dot16v(const float* a, const float* b){
  const float4* A = (const float4*)a;
  const float4* B = (const float4*)b;
  float s = 0.f;
#pragma unroll
  for (int q = 0; q < 4; ++q){
    float4 x = A[q], y = B[q];
    s += x.x*y.x; s += x.y*y.y; s += x.z*y.z; s += x.w*y.w;
  }
  return s;
}

// ---------- threefry2x32 (JAX-exact) ----------
__device__ __forceinline__ unsigned rotl32(unsigned x, int r){ return (x << r) | (x >> (32 - r)); }

__device__ void threefry2x32(unsigned k0, unsigned k1, unsigned c0, unsigned c1,
                             unsigned &o0, unsigned &o1){
  unsigned ks2 = k0 ^ k1 ^ 0x1BD11BDAu;
  unsigned x0 = c0 + k0, x1 = c1 + k1;
#define TF_R(r) { x0 += x1; x1 = rotl32(x1, r); x1 ^= x0; }
  TF_R(13) TF_R(15) TF_R(26) TF_R(6)
  x0 += k1;  x1 += ks2 + 1u;
  TF_R(17) TF_R(29) TF_R(16) TF_R(24)
  x0 += ks2; x1 += k0 + 2u;
  TF_R(13) TF_R(15) TF_R(26) TF_R(6)
  x0 += k0;  x1 += k1 + 3u;
  TF_R(17) TF_R(29) TF_R(16) TF_R(24)
  x0 += k1;  x1 += ks2 + 4u;
  TF_R(13) TF_R(15) TF_R(26) TF_R(6)
  x0 += ks2; x1 += k0 + 5u;
#undef TF_R
  o0 = x0; o1 = x1;
}

// XLA f32 erf_inv polynomial (Giles)
__device__ float erfinv32(float x){
  float w = -log1pf(-x*x);
  float p;
  if (w < 5.0f) {
    w -= 2.5f;
    p =  2.81022636e-08f;
    p = fmaf(p, w,  3.43273939e-07f);
    p = fmaf(p, w, -3.5233877e-06f);
    p = fmaf(p, w, -4.39150654e-06f);
    p = fmaf(p, w,  0.00021858087f);
    p = fmaf(p, w, -0.00125372503f);
    p = fmaf(p, w, -0.00417768164f);
    p = fmaf(p, w,  0.246640727f);
    p = fmaf(p, w,  1.50140941f);
  } else {
    w = sqrtf(w) - 3.0f;
    p = -0.000200214257f;
    p = fmaf(p, w,  0.000100950558f);
    p = fmaf(p, w,  0.00134934322f);
    p = fmaf(p, w, -0.00367342844f);
    p = fmaf(p, w,  0.00573950773f);
    p = fmaf(p, w, -0.0076224613f);
    p = fmaf(p, w,  0.00943887047f);
    p = fmaf(p, w,  1.00167406f);
    p = fmaf(p, w,  2.83297682f);
  }
  return p * x;
}

__device__ __forceinline__ float bits_to_normal(unsigned b){
  float f = __uint_as_float((b >> 9) | 0x3f800000u) - 1.0f; // [0,1)
  const float lo = -0.99999994f;                            // nextafter(-1,0)
  float u = fmaxf(lo, f * 2.0f + lo);                       // (hi-lo) rounds to 2.0f
  return 1.41421356f * erfinv32(u);
}

// draw index p in [0,16000): JAX splits counters as (p, p+8000)
__device__ float eps_val(unsigned k0, unsigned k1, int p){
  unsigned o0, o1;
  if (p < 8000) { threefry2x32(k0,k1,(unsigned)p,(unsigned)(p+8000),o0,o1); return bits_to_normal(o0); }
  threefry2x32(k0,k1,(unsigned)(p-8000),(unsigned)p,o0,o1); return bits_to_normal(o1);
}

// key(42) split into 64 keys; key_b = (out[2b], out[2b+1]) of threefry(key, iota(128))
__device__ void batch_key(int b, unsigned &k0, unsigned &k1){
  unsigned a0, a1, d;
  if (b < 32) {
    threefry2x32(0u,42u, (unsigned)(2*b),   (unsigned)(2*b+64), a0, d);
    threefry2x32(0u,42u, (unsigned)(2*b+1), (unsigned)(2*b+65), a1, d);
  } else {
    threefry2x32(0u,42u, (unsigned)(2*b-64), (unsigned)(2*b),   d, a0);
    threefry2x32(0u,42u, (unsigned)(2*b-63), (unsigned)(2*b+1), d, a1);
  }
  k0 = a0; k1 = a1;
}

// parallel in-place Cholesky (lower), 256 threads, 2 barriers/column
__device__ __forceinline__ void chol16(float (*C)[ST], int i, int j){
  for (int k = 0; k < 16; ++k) {
    float s    = sqrtf(C[k][k]);
    float invs = 1.0f / s;
    float cik  = C[i][k];
    float cjk  = C[j][k];
    __syncthreads();
    if (j == k) {
      if (i == k)     C[k][k] = s;
      else if (i > k) C[i][k] = cik * invs;
    } else if (j > k && j <= i) {
      C[i][j] -= (cik*invs) * (cjk*invs);
    }
    __syncthreads();
  }
}

// =====================================================================
// Pass 1: forward information filter.
//   stores Minv_t -> EXXNT slot t, Mim_t -> EX slot t (t=0..998),
//   VT -> EXXT slot 999, mT -> EX slot 999, logZ -> kl[b]
// =====================================================================
__global__ __launch_bounds__(256) void lds_fwd(
    const float* __restrict__ Jrd, const float* __restrict__ hr,
    const float* __restrict__ loc, const float* __restrict__ Taup,
    const float* __restrict__ Lamp, const float* __restrict__ X,
    float* __restrict__ out)
{
  const int b = blockIdx.x, tid = threadIdx.x;
  const int i = tid >> 4, j = tid & 15;

  __shared__ float tau[16][ST], lam[16][ST], AtL[16][ST], AtLA[16][ST], fJ[16][ST];
  __shared__ float As[16][ST], Tp[16][ST], Lp[16][ST];
  __shared__ float Aug[16][49];
  __shared__ float AtLbv[16], Lbv[16], tmu[16], bvv[16], locv[16], fhv[16], mv[16], Mimv[16];

  // ---- stage inputs ----
  Tp[i][j] = Taup[tid];
  Lp[i][j] = Lamp[tid];
  As[i][j] = X[i*17 + j];
  if (tid < 16) { locv[tid] = loc[tid]; bvv[tid] = X[tid*17 + 16]; }
  __syncthreads();

  // tau = Tp Tp^T + 1e-8 I ; lam = Lp Lp^T + 1e-8 I
  float a0 = 0.f, a1 = 0.f;
#pragma unroll
  for (int k = 0; k < 16; ++k) { a0 += Tp[i][k]*Tp[j][k]; a1 += Lp[i][k]*Lp[j][k]; }
  tau[i][j] = a0 + (i==j ? 1e-8f : 0.f);
  lam[i][j] = a1 + (i==j ? 1e-8f : 0.f);
  __syncthreads();

  // AtL = A^T lam
  a0 = 0.f;
#pragma unroll
  for (int k = 0; k < 16; ++k) a0 += As[k][i]*lam[k][j];
  AtL[i][j] = a0;
  __syncthreads();

  // AtLA = AtL A ; vectors
  a0 = 0.f;
#pragma unroll
  for (int k = 0; k < 16; ++k) a0 += AtL[i][k]*As[k][j];
  AtLA[i][j] = a0;
  float s_AtLb = red16(AtL[i][j]*bvv[j]);
  float s_Lb   = red16(lam[i][j]*bvv[j]);
  float s_tmu  = red16(tau[i][j]*locv[j]);
  if (j == 0) { AtLbv[i] = s_AtLb; Lbv[i] = s_Lb; tmu[i] = s_tmu; }
  __syncthreads();

  // slogdet(lam), slogdet(tau) via GE (pivots of SPD, no pivoting)
  Aug[i][j]    = lam[i][j];
  Aug[i][16+j] = tau[i][j];
  __syncthreads();
  float ld_lam = 0.f, ld_tau = 0.f;
  for (int k = 0; k < 16; ++k) {
    float pivL = Aug[k][k], pivT = Aug[k][16+k];
    ld_lam += __logf(pivL); ld_tau += __logf(pivT);
    float fL = (i > k) ? Aug[i][k]/pivL : 0.f;
    float fT = (i > k) ? Aug[i][16+k]/pivT : 0.f;
    float rkL = Aug[k][j], rkT = Aug[k][16+j];
    __syncthreads();
    if (i > k) { Aug[i][j] -= fL*rkL; Aug[i][16+j] -= fT*rkT; }
    __syncthreads();
  }
  float dBL = red16(bvv[j]*Lbv[j]);
  float dLT = red16(locv[j]*tmu[j]);
  const float trans_const = -0.5f*dBL + 0.5f*ld_lam;
  const float init_const  = -0.5f*dLT + 0.5f*ld_tau;

  // ---- init fJ, fh ----
  const float* JrdB = Jrd + (long long)b*TT*16;
  const float* hrB  = hr  + (long long)b*TT*16;
  float* EXXNTb = out + EXXNT_OFF + (long long)b*(TT-1)*256;
  float* EXb    = out + EX_OFF    + (long long)b*TT*16;
  float* EXXTb  = out + EXXT_OFF  + (long long)b*TT*256;

  fJ[i][j] = tau[i][j] + ((i==j) ? (JrdB[i] + 0.5f) : 0.f);
  if (j == 0) fhv[i] = tmu[i] + hrB[i];
  __syncthreads();

  float lz = 0.f;
  float jr_nx = (i==j) ? JrdB[16 + i] : 0.f;   // row t+1 = 1
  float hr_nx = (j==0) ? hrB[16 + i]  : 0.f;

  for (int t = 0; t < TT-1; ++t) {
    // build [M | AtL | I], save m = fh - AtLb
    Aug[i][j]    = fJ[i][j] + AtLA[i][j];
    Aug[i][16+j] = AtL[i][j];
    Aug[i][32+j] = (i==j) ? 1.f : 0.f;
    if (j == 0) mv[i] = fhv[i] - AtLbv[i];
    __syncthreads();

    float jr_cur = jr_nx, hr_cur = hr_nx;
    if (t + 2 < TT) {                 // prefetch row t+2
      if (i==j) jr_nx = JrdB[(t+2)*16 + i];
      if (j==0) hr_nx = hrB[(t+2)*16 + i];
    }

    // Gauss-Jordan with log-pivot accumulation
    float ld = 0.f;
    for (int k = 0; k < 16; ++k) {
      float piv  = Aug[k][k];
      float invp = 1.0f / piv;
      ld += __logf(piv);
      float f   = Aug[i][k] * invp;
      float rk0 = Aug[k][j], rk1 = Aug[k][16+j], rk2 = Aug[k][32+j];
      __syncthreads();
      if (i == k) {
        Aug[k][j]    = rk0 * invp;
        Aug[k][16+j] = rk1 * invp;
        Aug[k][32+j] = rk2 * invp;
      } else {
        Aug[i][j]    -= f * rk0;
        Aug[i][16+j] -= f * rk1;
        Aug[i][32+j] -= f * rk2;
      }
      __syncthreads();
    }

    // Minv -> EXXNT[t]; Mim = Minv m -> EX[t]
    float minv_ij = Aug[i][32+j];
    EXXNTb[(long long)t*256 + tid] = minv_ij;
    float mim = red16(minv_ij * mv[j]);
    if (j == 0) { Mimv[i] = mim; EXb[t*16 + i] = mim; }
    __syncthreads();

    float dmm = red16(mv[j] * Mimv[j]);
    lz += 0.5f*dmm - 0.5f*ld + trans_const;

    // fJ_new = lam - AtL^T (Minv AtL) + diag(jr+0.5); fh_new = Lb + AtL^T Mim + hr
    float accJ = 0.f, acch = 0.f;
#pragma unroll
    for (int k = 0; k < 16; ++k) {
      float atlki = AtL[k][i];
      accJ += atlki * Aug[k][16+j];
      acch += atlki * Mimv[k];
    }
    float fJn = lam[i][j] - accJ + ((i==j) ? (jr_cur + 0.5f) : 0.f);
    fJ[i][j] = fJn;
    if (j == 0) fhv[i] = Lbv[i] + acch + hr_cur;
    __syncthreads();
  }

  // ---- tail: VT = inv(fJT), mT, logZ ----
  Aug[i][j]    = fJ[i][j];
  Aug[i][16+j] = (i==j) ? 1.f : 0.f;
  if (j == 0) mv[i] = fhv[i];
  __syncthreads();
  float ldT = 0.f;
  for (int k = 0; k < 16; ++k) {
    float piv  = Aug[k][k];
    float invp = 1.0f / piv;
    ldT += __logf(piv);
    float f   = Aug[i][k] * invp;
    float rk0 = Aug[k][j], rk1 = Aug[k][16+j];
    __syncthreads();
    if (i == k) { Aug[k][j] = rk0*invp; Aug[k][16+j] = rk1*invp; }
    else        { Aug[i][j] -= f*rk0;  Aug[i][16+j] -= f*rk1; }
    __syncthreads();
  }
  float vt_ij = Aug[i][16+j];
  EXXTb[(long long)(TT-1)*256 + tid] = vt_ij;
  float mT = red16(vt_ij * mv[j]);
  if (j == 0) { Mimv[i] = mT; EXb[(TT-1)*16 + i] = mT; }
  __syncthreads();
  float dfm = red16(mv[j] * Mimv[j]);
  if (tid == 0) out[KL_OFF + b] = lz + init_const + 0.5f*dfm - 0.5f*ldT;
}

// =====================================================================
// Pass 2: backward RTS smoother. Reads Minv/Mim from EXXNT/EX slots,
// overwrites with C_t / m_t; writes raw V_t to EXXT; finishes kl[b].
// =====================================================================
__global__ __launch_bounds__(256) void lds_bwd(
    const float* __restrict__ Jrd, const float* __restrict__ hr,
    const float* __restrict__ Lamp, const float* __restrict__ X,
    float* __restrict__ out)
{
  const int b = blockIdx.x, tid = threadIdx.x;
  const int i = tid >> 4, j = tid & 15;

  __shared__ float AtLT[16][ST], Pi[16][ST], G[16][ST], V[16][ST], W[16][ST];
  __shared__ float lamS[16][ST], As[16][ST];
  __shared__ float mnv[16], pmv[16], mvv[16];

  // setup: AtLT[j][k] = AtL[k][j]
  As[i][j] = X[i*17 + j];
  Pi[i][j] = Lamp[tid];     // stage Lam_p in Pi
  __syncthreads();
  float a = 0.f;
#pragma unroll
  for (int k = 0; k < 16; ++k) a += Pi[i][k]*Pi[j][k];
  __syncthreads();
  lamS[i][j] = a + (i==j ? 1e-8f : 0.f);
  __syncthreads();
  a = 0.f;
#pragma unroll
  for (int k = 0; k < 16; ++k) a += As[k][j]*lamS[k][i];   // AtL[j][i]
  AtLT[i][j] = a;
  __syncthreads();

  const float* JrdB = Jrd + (long long)b*TT*16;
  const float* hrB  = hr  + (long long)b*TT*16;
  float* EXXNTb = out + EXXNT_OFF + (long long)b*(TT-1)*256;
  float* EXb    = out + EX_OFF    + (long long)b*TT*16;
  float* EXXTb  = out + EXXT_OFF  + (long long)b*TT*256;

  V[i][j] = EXXTb[(long long)(TT-1)*256 + tid];
  if (tid < 16) mnv[tid] = EXb[(TT-1)*16 + tid];
  float logZ = out[KL_OFF + b];
  __syncthreads();

  float klacc = 0.f;
  {
    float p = 0.f;
    if (i == 0) {
      float jr = JrdB[(TT-1)*16 + j] + 0.5f;
      float hv = hrB[(TT-1)*16 + j];
      float m  = mnv[j];
      p = -0.5f*jr*(V[j][j] + m*m) + hv*m;
    }
    p = red16(p);
    if (tid == 0) klacc += p;
  }

  // prefetch t = 998
  float regPi = EXXNTb[(long long)(TT-2)*256 + tid];
  float regpm = (tid<16) ? EXb[(TT-2)*16 + tid]  : 0.f;
  float regjr = (tid<16) ? JrdB[(TT-2)*16 + tid] : 0.f;
  float reghr = (tid<16) ? hrB[(TT-2)*16 + tid]  : 0.f;

  for (int t = TT-2; t >= 0; --t) {
    Pi[i][j] = regPi;
    if (tid < 16) pmv[tid] = regpm;
    float jr_c = regjr, hr_c = reghr;
    __syncthreads();
    if (t > 0) {
      regPi = EXXNTb[(long long)(t-1)*256 + tid];
      if (tid < 16) { regpm = EXb[(t-1)*16 + tid]; regjr = JrdB[(t-1)*16 + tid]; reghr = hrB[(t-1)*16 + tid]; }
    }
    // G = Pi AtL (row.row via AtLT); m_t = pm + G mn
    float g = dot16v(&Pi[i][0], &AtLT[j][0]);
    G[i][j] = g;
    float pm_ = red16(g * mnv[j]);
    float mval = pmv[i] + pm_;
    if (j == 0) { mvv[i] = mval; EXb[t*16 + i] = mval; }
    __syncthreads();
    // C_t = W = G V (V symmetric -> row.row)
    float w = dot16v(&G[i][0], &V[j][0]);
    W[i][j] = w;
    EXXNTb[(long long)t*256 + tid] = w;
    __syncthreads();
    // V_t = Pi + W G^T (row.row)
    float vnew = Pi[i][j] + dot16v(&W[i][0], &G[j][0]);
    V[i][j] = vnew;
    EXXTb[(long long)t*256 + tid] = vnew;
    __syncthreads();
    // kl term at t, roll mn
    float p = 0.f;
    if (i == 0) {
      float m = mvv[j];
      p = -0.5f*(jr_c + 0.5f)*(V[j][j] + m*m) + hr_c*m;
      mnv[j] = m;
    }
    p = red16(p);
    if (tid == 0) klacc += p;
    __syncthreads();
  }
  if (tid == 0) out[KL_OFF + b] = klacc - logZ;
}

// =====================================================================
// Pass 3: sampler + moment finalization (EXXT += m m^T, EXXNT += m m'^T)
// =====================================================================
__global__ __launch_bounds__(256) void lds_smp(float* __restrict__ out)
{
  const int b = blockIdx.x, tid = threadIdx.x;
  const int i = tid >> 4, j = tid & 15;

  __shared__ float Vt[16][ST], Vn[16][ST], CtT[16][ST], KT[16][ST], CV[16][ST];
  __shared__ float Aug[16][33];
  __shared__ float mtv[16], mnv[16], ztv[16];
  __shared__ float ebuf[16][16];

  float* zB     = out + Z_OFF     + (long long)b*TT*16;
  float* EXXTb  = out + EXXT_OFF  + (long long)b*TT*256;
  float* EXb    = out + EX_OFF    + (long long)b*TT*16;
  float* EXXNTb = out + EXXNT_OFF + (long long)b*(TT-1)*256;

  unsigned k0, k1; batch_key(b, k0, k1);
  ebuf[i][j] = eps_val(k0, k1, i*16 + j);   // rows 0..15

  float v0 = EXXTb[tid];
  Vt[i][j] = v0;
  CV[i][j] = v0 + (i==j ? 1e-6f : 0.f);
  if (tid < 16) mtv[tid] = EXb[tid];
  __syncthreads();

  chol16(CV, i, j);
  {
    float p = (j <= i) ? CV[i][j]*ebuf[0][j] : 0.f;
    p = red16(p);
    if (j == 0) { float z = mtv[i] + p; ztv[i] = z; zB[i] = z; }
  }
  // prefetch t = 0 inputs
  float regCt = EXXNTb[tid];
  float regVn = EXXTb[256 + tid];
  float regmn = (tid < 16) ? EXb[16 + tid] : 0.f;
  __syncthreads();

  for (int t = 0; t < TT-1; ++t) {
    if (((t+1) & 15) == 0) {                 // refill eps rows t+1..t+16
      int tt = t + 1 + i;
      if (tt < TT) ebuf[i][j] = eps_val(k0, k1, tt*16 + j);
    }
    float ct_ij = regCt;
    CtT[j][i] = ct_ij;
    Vn[i][j]  = regVn;
    if (tid < 16) mnv[tid] = regmn;
    Aug[i][j]    = Vt[i][j];
    Aug[i][16+j] = ct_ij;
    __syncthreads();
    if (t < TT-2) {
      regCt = EXXNTb[(long long)(t+1)*256 + tid];
      regVn = EXXTb[(long long)(t+2)*256 + tid];
      if (tid < 16) regmn = EXb[(t+2)*16 + tid];
    }
    // K = Vt^{-1} Ct  (GJ on [Vt | Ct])
    for (int k = 0; k < 16; ++k) {
      float piv  = Aug[k][k];
      float invp = 1.0f / piv;
      float f    = Aug[i][k] * invp;
      float rk0  = Aug[k][j], rk1 = Aug[k][16+j];
      __syncthreads();
      if (i == k) { Aug[k][j] = rk0*invp; Aug[k][16+j] = rk1*invp; }
      else        { Aug[i][j] -= f*rk0;  Aug[i][16+j] -= f*rk1; }
      __syncthreads();
    }
    KT[j][i] = Aug[i][16+j];
    __syncthreads();
    // condV = Vn - Ct^T K + jitter I
    CV[i][j] = Vn[i][j] - dot16v(&CtT[i][0], &KT[j][0]) + (i==j ? 1e-6f : 0.f);
    __syncthreads();
    chol16(CV, i, j);
    // z_{t+1} = mn + K^T (z_t - m_t) + L eps
    float zp = KT[i][j]*(ztv[j]-mtv[j]) + ((j <= i) ? CV[i][j]*ebuf[(t+1)&15][j] : 0.f);
    zp = red16(zp);
    // finalize moments at t
    EXXTb[(long long)t*256 + tid]  = Vt[i][j] + mtv[i]*mtv[j];
    EXXNTb[(long long)t*256 + tid] = ct_ij    + mtv[i]*mnv[j];
    __syncthreads();
    if (j == 0) { float z = mnv[i] + zp; ztv[i] = z; zB[(t+1)*16 + i] = z; mtv[i] = mnv[i]; }
    Vt[i][j] = Vn[i][j];
    __syncthreads();
  }
  EXXTb[(long long)(TT-1)*256 + tid] = Vt[i][j] + mtv[i]*mtv[j];
}

// =====================================================================
extern "C" void kernel_launch(void* const* d_in, const int* in_sizes, int n_in,
                              void* d_out, int out_size, void* d_ws, size_t ws_size,
                              hipStream_t stream) {
  (void)in_sizes; (void)n_in; (void)d_ws; (void)ws_size; (void)out_size;
  const float* Jrd  = (const float*)d_in[0];
  const float* hr   = (const float*)d_in[1];
  const float* loc  = (const float*)d_in[2];
  const float* Taup = (const float*)d_in[3];
  const float* Lamp = (const float*)d_in[4];
  const float* X    = (const float*)d_in[5];
  float* out = (float*)d_out;

  lds_fwd<<<64, 256, 0, stream>>>(Jrd, hr, loc, Taup, Lamp, X, out);
  lds_bwd<<<64, 256, 0, stream>>>(Jrd, hr, Lamp, X, out);
  lds_smp<<<64, 256, 0, stream>>>(out);
}

// Round 2
// 4926.111 us; speedup vs baseline: 2.9833x; 2.9833x over previous
//
#include <hip/hip_runtime.h>

// Problem constants
constexpr int TT = 1000;
constexpr int ST = 20;   // padded LDS row stride (16B-aligned rows)

// d_out layout (floats): z | kl | EXXT | EX | EXXNT
constexpr long long Z_OFF     = 0;
constexpr long long KL_OFF    = 1024000;
constexpr long long EXXT_OFF  = 1024064;
constexpr long long EX_OFF    = 17408064;
constexpr long long EXXNT_OFF = 18432064;

#define WSYNC() { __builtin_amdgcn_wave_barrier(); __builtin_amdgcn_sched_barrier(0); }

// ---------- helpers ----------
__device__ __forceinline__ float dot4(float4 a, float4 b){
  return a.x*b.x + a.y*b.y + a.z*b.z + a.w*b.w;
}
__device__ __forceinline__ float xor16sum(float v){
  v += __shfl_xor(v, 1); v += __shfl_xor(v, 2);
  v += __shfl_xor(v, 4); v += __shfl_xor(v, 8);
  return v;  // sum over the 16-lane j-group, replicated
}
// rows r0..r3 hold values for rows 4*rgrp+q, replicated within each 16-lane group.
// Returns element [j] (column form).
__device__ __forceinline__ float row2col(float r0, float r1, float r2, float r3, int j){
  int s = (j >> 2) << 4;
  float t0 = __shfl(r0, s), t1 = __shfl(r1, s), t2 = __shfl(r2, s), t3 = __shfl(r3, s);
  float lo = (j & 1) ? t1 : t0, hi = (j & 1) ? t3 : t2;
  return (j & 2) ? hi : lo;
}

// In-place Gauss-Jordan sweep: aM (rows 4*rgrp+q, col j) -> inv(aM); aS -> inv(M)*S.
// Optionally accumulates logdet (SPD, no pivoting).
template<bool WITH_S, bool LOGDET>
__device__ __forceinline__ void sweep16(float* aM, float* aS, const int rgrp, const int j, float& ld){
#pragma unroll
  for (int k = 0; k < 16; ++k){
    const int kg = k >> 2, kq = k & 3;
    const int psrc = (kg << 4) | j;
    float prM = __shfl(aM[kq], psrc);
    float prS = WITH_S ? __shfl(aS[kq], psrc) : 0.f;
    float piv = __shfl(aM[kq], (kg << 4) | k);
    float f0 = __shfl(aM[0], (rgrp << 4) | k);
    float f1 = __shfl(aM[1], (rgrp << 4) | k);
    float f2 = __shfl(aM[2], (rgrp << 4) | k);
    float f3 = __shfl(aM[3], (rgrp << 4) | k);
    float invp = __builtin_amdgcn_rcpf(piv);
    if (LOGDET) ld += __logf(piv);
    const bool pivCol = (j == k);
    const bool pivG   = (rgrp == kg);
    float fi[4] = {f0*invp, f1*invp, f2*invp, f3*invp};
#pragma unroll
    for (int q = 0; q < 4; ++q){
      const bool isPivRow = pivG && (q == kq);
      float nM = aM[q] - fi[q]*prM;
      if (pivCol)   nM = -fi[q];
      if (isPivRow) nM = pivCol ? invp : prM*invp;
      aM[q] = nM;
      if (WITH_S){
        float nS = aS[q] - fi[q]*prS;
        if (isPivRow) nS = prS*invp;
        aS[q] = nS;
      }
    }
  }
}

// Register-resident Cholesky (lower). cv[q] = A[4*rgrp+q][j] on entry; L in lower incl diag on exit.
__device__ __forceinline__ void chol16r(float* cv, const int rgrp, const int j){
#pragma unroll
  for (int k = 0; k < 16; ++k){
    const int kg = k >> 2, kq = k & 3;
    float piv = __shfl(cv[kq], (kg << 4) | k);
    float s   = sqrtf(piv);
    float inv = __builtin_amdgcn_rcpf(s);
    const int srcjk = ((j >> 2) << 4) | k;
    float t0 = __shfl(cv[0], srcjk), t1 = __shfl(cv[1], srcjk);
    float t2 = __shfl(cv[2], srcjk), t3 = __shfl(cv[3], srcjk);
    float lo = (j & 1) ? t1 : t0, hi = (j & 1) ? t3 : t2;
    float Ljk = ((j & 2) ? hi : lo) * inv;
    const int srcik = (rgrp << 4) | k;
    float a0 = __shfl(cv[0], srcik), a1 = __shfl(cv[1], srcik);
    float a2 = __shfl(cv[2], srcik), a3 = __shfl(cv[3], srcik);
    float Lik[4] = {a0*inv, a1*inv, a2*inv, a3*inv};
#pragma unroll
    for (int q = 0; q < 4; ++q){
      int iq = 4*rgrp + q;
      float v = cv[q];
      if (j == k)                 v = (iq > k) ? Lik[q] : ((iq == k) ? s : v);
      else if (j > k && iq > k)   v = v - Lik[q]*Ljk;
      cv[q] = v;
    }
  }
}

// ---------- threefry2x32 (JAX-exact) ----------
__device__ __forceinline__ unsigned rotl32(unsigned x, int r){ return (x << r) | (x >> (32 - r)); }

__device__ void threefry2x32(unsigned k0, unsigned k1, unsigned c0, unsigned c1,
                             unsigned &o0, unsigned &o1){
  unsigned ks2 = k0 ^ k1 ^ 0x1BD11BDAu;
  unsigned x0 = c0 + k0, x1 = c1 + k1;
#define TF_R(r) { x0 += x1; x1 = rotl32(x1, r); x1 ^= x0; }
  TF_R(13) TF_R(15) TF_R(26) TF_R(6)
  x0 += k1;  x1 += ks2 + 1u;
  TF_R(17) TF_R(29) TF_R(16) TF_R(24)
  x0 += ks2; x1 += k0 + 2u;
  TF_R(13) TF_R(15) TF_R(26) TF_R(6)
  x0 += k0;  x1 += k1 + 3u;
  TF_R(17) TF_R(29) TF_R(16) TF_R(24)
  x0 += k1;  x1 += ks2 + 4u;
  TF_R(13) TF_R(15) TF_R(26) TF_R(6)
  x0 += ks2; x1 += k0 + 5u;
#undef TF_R
  o0 = x0; o1 = x1;
}

__device__ float erfinv32(float x){
  float w = -log1pf(-x*x);
  float p;
  if (w < 5.0f) {
    w -= 2.5f;
    p =  2.81022636e-08f;
    p = fmaf(p, w,  3.43273939e-07f);
    p = fmaf(p, w, -3.5233877e-06f);
    p = fmaf(p, w, -4.39150654e-06f);
    p = fmaf(p, w,  0.00021858087f);
    p = fmaf(p, w, -0.00125372503f);
    p = fmaf(p, w, -0.00417768164f);
    p = fmaf(p, w,  0.246640727f);
    p = fmaf(p, w,  1.50140941f);
  } else {
    w = sqrtf(w) - 3.0f;
    p = -0.000200214257f;
    p = fmaf(p, w,  0.000100950558f);
    p = fmaf(p, w,  0.00134934322f);
    p = fmaf(p, w, -0.00367342844f);
    p = fmaf(p, w,  0.00573950773f);
    p = fmaf(p, w, -0.0076224613f);
    p = fmaf(p, w,  0.00943887047f);
    p = fmaf(p, w,  1.00167406f);
    p = fmaf(p, w,  2.83297682f);
  }
  return p * x;
}

__device__ __forceinline__ float bits_to_normal(unsigned b){
  float f = __uint_as_float((b >> 9) | 0x3f800000u) - 1.0f;
  const float lo = -0.99999994f;
  float u = fmaxf(lo, f * 2.0f + lo);
  return 1.41421356f * erfinv32(u);
}

__device__ float eps_val(unsigned k0, unsigned k1, int p){
  unsigned o0, o1;
  if (p < 8000) { threefry2x32(k0,k1,(unsigned)p,(unsigned)(p+8000),o0,o1); return bits_to_normal(o0); }
  threefry2x32(k0,k1,(unsigned)(p-8000),(unsigned)p,o0,o1); return bits_to_normal(o1);
}

__device__ void batch_key(int b, unsigned &k0, unsigned &k1){
  unsigned a0, a1, d;
  if (b < 32) {
    threefry2x32(0u,42u, (unsigned)(2*b),   (unsigned)(2*b+64), a0, d);
    threefry2x32(0u,42u, (unsigned)(2*b+1), (unsigned)(2*b+65), a1, d);
  } else {
    threefry2x32(0u,42u, (unsigned)(2*b-64), (unsigned)(2*b),   d, a0);
    threefry2x32(0u,42u, (unsigned)(2*b-63), (unsigned)(2*b+1), d, a1);
  }
  k0 = a0; k1 = a1;
}

// =====================================================================
// Pass 1: forward information filter. One wave (64 threads) per batch.
// Lane (rgrp=tid>>4, j=tid&15) owns matrix rows 4*rgrp+q (q=0..3) at column j.
// Stores: EXXNT[t] <- Minv_t (sym, float4), EX[t] <- Mim_t (t<=998),
//         EXXT[999] <- VT raw, EX[999] <- mT, kl[b] <- logZ
// =====================================================================
__global__ __launch_bounds__(64) void lds_fwd(
    const float* __restrict__ Jrd, const float* __restrict__ hr,
    const float* __restrict__ loc, const float* __restrict__ Taup,
    const float* __restrict__ Lamp, const float* __restrict__ X,
    float* __restrict__ out)
{
  const int b = blockIdx.x, tid = threadIdx.x;
  const int j = tid & 15, rgrp = tid >> 4;

  __shared__ __align__(16) float sA[16][ST], sTp[16][ST], sLp[16][ST];
  __shared__ __align__(16) float sTau[16][ST], sLam[16][ST], sAtL[16][ST], sAtLT[16][ST];
  __shared__ __align__(16) float STL[16][ST];
  __shared__ __align__(16) float mL[16];
  __shared__ float vecb[16], vloc[16];

  // ---- setup ----
#pragma unroll
  for (int q = 0; q < 4; ++q){
    int i = 4*rgrp + q;
    sTp[i][j] = Taup[i*16 + j];
    sLp[i][j] = Lamp[i*16 + j];
    sA[i][j]  = X[i*17 + j];
  }
  if (tid < 16){ vloc[tid] = loc[tid]; vecb[tid] = X[tid*17 + 16]; }
  __syncthreads();

#pragma unroll
  for (int q = 0; q < 4; ++q){
    int i = 4*rgrp + q;
    float s0 = 0.f, s1 = 0.f;
    for (int k = 0; k < 16; ++k){ s0 += sTp[i][k]*sTp[j][k]; s1 += sLp[i][k]*sLp[j][k]; }
    sTau[i][j] = s0 + (i==j ? 1e-8f : 0.f);
    sLam[i][j] = s1 + (i==j ? 1e-8f : 0.f);
  }
  __syncthreads();

  float atlrow[4];
#pragma unroll
  for (int q = 0; q < 4; ++q){
    int i = 4*rgrp + q;
    float s = 0.f;
    for (int k = 0; k < 16; ++k) s += sA[k][i]*sLam[k][j];
    atlrow[q] = s;
  }
  __syncthreads();
#pragma unroll
  for (int q = 0; q < 4; ++q){
    int i = 4*rgrp + q;
    sAtL[i][j] = atlrow[q];
    sAtLT[j][i] = atlrow[q];
  }
  __syncthreads();

  float atla[4];
#pragma unroll
  for (int q = 0; q < 4; ++q){
    int i = 4*rgrp + q;
    float s = 0.f;
    for (int k = 0; k < 16; ++k) s += sAtL[i][k]*sA[k][j];
    atla[q] = s;
  }

  float b_j = vecb[j], loc_j = vloc[j];
  float pA[4], pL[4], pT[4];
#pragma unroll
  for (int q = 0; q < 4; ++q){
    int i = 4*rgrp + q;
    pA[q] = atlrow[q]*b_j;
    pL[q] = sLam[i][j]*b_j;
    pT[q] = sTau[i][j]*loc_j;
  }
#pragma unroll
  for (int q = 0; q < 4; ++q){ pA[q] = xor16sum(pA[q]); pL[q] = xor16sum(pL[q]); pT[q] = xor16sum(pT[q]); }
  float AtLb_j = row2col(pA[0],pA[1],pA[2],pA[3], j);
  float Lb_j   = row2col(pL[0],pL[1],pL[2],pL[3], j);
  float tmu_j  = row2col(pT[0],pT[1],pT[2],pT[3], j);

  // logdets of lam and tau via sweeps on register copies
  float ld_lam = 0.f, ld_tau = 0.f;
  {
    float r[4], d[4];
#pragma unroll
    for (int q = 0; q < 4; ++q){ r[q] = sLam[4*rgrp+q][j]; d[q] = 0.f; }
    sweep16<false,true>(r, d, rgrp, j, ld_lam);
#pragma unroll
    for (int q = 0; q < 4; ++q){ r[q] = sTau[4*rgrp+q][j]; }
    sweep16<false,true>(r, d, rgrp, j, ld_tau);
  }
  float dBL = xor16sum(b_j*Lb_j);
  float dLT = xor16sum(loc_j*tmu_j);
  const float trans_const = -0.5f*dBL + 0.5f*ld_lam;
  const float init_const  = -0.5f*dLT + 0.5f*ld_tau;

  const float* JrdB = Jrd + (long long)b*TT*16;
  const float* hrB  = hr  + (long long)b*TT*16;
  float* EXXNTb = out + EXXNT_OFF + (long long)b*(TT-1)*256;
  float* EXb    = out + EX_OFF    + (long long)b*TT*16;
  float* EXXTb  = out + EXXT_OFF  + (long long)b*TT*256;

  float lam4[4], fj[4];
#pragma unroll
  for (int q = 0; q < 4; ++q){
    int i = 4*rgrp + q;
    lam4[q] = sLam[i][j];
    fj[q]   = sTau[i][j] + ((i==j) ? (JrdB[j] + 0.5f) : 0.f);
  }
  float fh_j = tmu_j + hrB[j];
  float jr_nx = JrdB[16 + j], hr_nx = hrB[16 + j];
  float lz = 0.f;

#pragma unroll 1
  for (int t = 0; t < TT-1; ++t){
    float m_j = fh_j - AtLb_j;
    float aM[4], aS[4];
#pragma unroll
    for (int q = 0; q < 4; ++q){ aM[q] = fj[q] + atla[q]; aS[q] = atlrow[q]; }
    float ld = 0.f;
    sweep16<true,true>(aM, aS, rgrp, j, ld);

    // Minv symmetric: aM[q] = Minv[4rgrp+q][j] = Minv[j][4rgrp+q] -> float4 row store
    *(float4*)(EXXNTb + (long long)t*256 + j*16 + 4*rgrp) = make_float4(aM[0],aM[1],aM[2],aM[3]);

    float p0 = aM[0]*m_j, p1 = aM[1]*m_j, p2 = aM[2]*m_j, p3 = aM[3]*m_j;
    p0 = xor16sum(p0); p1 = xor16sum(p1); p2 = xor16sum(p2); p3 = xor16sum(p3);
    float mim_j = row2col(p0,p1,p2,p3, j);
    if (rgrp == 0) EXb[t*16 + j] = mim_j;
    float dm = xor16sum(m_j * mim_j);
    lz += 0.5f*dm - 0.5f*ld + trans_const;

    *(float4*)&STL[j][4*rgrp] = make_float4(aS[0],aS[1],aS[2],aS[3]);  // S^T rows
    if (rgrp == 0) mL[j] = mim_j;
    WSYNC();

    float4 st0 = *(float4*)&STL[j][0],  st1 = *(float4*)&STL[j][4];
    float4 st2 = *(float4*)&STL[j][8],  st3 = *(float4*)&STL[j][12];
    float4 ml0 = *(float4*)&mL[0], ml1 = *(float4*)&mL[4];
    float4 ml2 = *(float4*)&mL[8], ml3 = *(float4*)&mL[12];

    float jr_c = jr_nx, hr_c = hr_nx;
    if (t + 2 < TT){ jr_nx = JrdB[(t+2)*16 + j]; hr_nx = hrB[(t+2)*16 + j]; }

    float Cq[4], ach[4];
#pragma unroll
    for (int q = 0; q < 4; ++q){
      int i = 4*rgrp + q;
      float4 a0 = *(float4*)&sAtLT[i][0],  a1 = *(float4*)&sAtLT[i][4];
      float4 a2 = *(float4*)&sAtLT[i][8],  a3 = *(float4*)&sAtLT[i][12];
      Cq[q]  = dot4(a0,st0) + dot4(a1,st1) + dot4(a2,st2) + dot4(a3,st3);
      ach[q] = dot4(a0,ml0) + dot4(a1,ml1) + dot4(a2,ml2) + dot4(a3,ml3);
    }
#pragma unroll
    for (int q = 0; q < 4; ++q){
      int i = 4*rgrp + q;
      fj[q] = lam4[q] - Cq[q] + ((i==j) ? (jr_c + 0.5f) : 0.f);
    }
    float ach_j = row2col(ach[0],ach[1],ach[2],ach[3], j);
    fh_j = Lb_j + ach_j + hr_c;
    WSYNC();
  }

  // tail: VT = inv(fJT), mT, logZ
  {
    float aM[4], d[4];
#pragma unroll
    for (int q = 0; q < 4; ++q){ aM[q] = fj[q]; d[q] = 0.f; }
    float ldT = 0.f;
    sweep16<false,true>(aM, d, rgrp, j, ldT);
    *(float4*)(EXXTb + (long long)(TT-1)*256 + j*16 + 4*rgrp) = make_float4(aM[0],aM[1],aM[2],aM[3]);
    float p0 = aM[0]*fh_j, p1 = aM[1]*fh_j, p2 = aM[2]*fh_j, p3 = aM[3]*fh_j;
    p0 = xor16sum(p0); p1 = xor16sum(p1); p2 = xor16sum(p2); p3 = xor16sum(p3);
    float mT_j = row2col(p0,p1,p2,p3, j);
    if (rgrp == 0) EXb[(TT-1)*16 + j] = mT_j;
    float dfm = xor16sum(fh_j * mT_j);
    if (tid == 0) out[KL_OFF + b] = lz + init_const + 0.5f*dfm - 0.5f*ldT;
  }
}

// =====================================================================
// Pass 2: backward RTS smoother. One wave per batch.
// Reads Minv(EXXNT)/Mim(EX); writes m_t -> EX (final), C_t -> EXXNT,
// V_t raw -> EXXT; kl[b] final.
// =====================================================================
__global__ __launch_bounds__(64) void lds_bwd(
    const float* __restrict__ Jrd, const float* __restrict__ hr,
    const float* __restrict__ Lamp, const float* __restrict__ X,
    float* __restrict__ out)
{
  const int b = blockIdx.x, tid = threadIdx.x;
  const int j = tid & 15, rgrp = tid >> 4;

  __shared__ __align__(16) float sA[16][ST], sLp[16][ST], sLam[16][ST], sAtLT[16][ST];
  __shared__ __align__(16) float PiL[16][ST], GL[16][ST], WL[16][ST], VL[16][ST];

  // setup: AtLT rows (AtLT[j][k] = AtL[k][j])
#pragma unroll
  for (int q = 0; q < 4; ++q){
    int i = 4*rgrp + q;
    sLp[i][j] = Lamp[i*16 + j];
    sA[i][j]  = X[i*17 + j];
  }
  __syncthreads();
#pragma unroll
  for (int q = 0; q < 4; ++q){
    int i = 4*rgrp + q;
    float s = 0.f;
    for (int k = 0; k < 16; ++k) s += sLp[i][k]*sLp[j][k];
    sLam[i][j] = s + (i==j ? 1e-8f : 0.f);
  }
  __syncthreads();
#pragma unroll
  for (int q = 0; q < 4; ++q){
    int i = 4*rgrp + q;
    float s = 0.f;
    for (int k = 0; k < 16; ++k) s += sA[k][i]*sLam[k][j];   // AtL[i][j]
    sAtLT[j][i] = s;
  }
  __syncthreads();
  float4 atltr0 = *(float4*)&sAtLT[j][0],  atltr1 = *(float4*)&sAtLT[j][4];
  float4 atltr2 = *(float4*)&sAtLT[j][8],  atltr3 = *(float4*)&sAtLT[j][12];

  const float* JrdB = Jrd + (long long)b*TT*16;
  const float* hrB  = hr  + (long long)b*TT*16;
  float* EXXNTb = out + EXXNT_OFF + (long long)b*(TT-1)*256;
  float* EXb    = out + EX_OFF    + (long long)b*TT*16;
  float* EXXTb  = out + EXXT_OFF  + (long long)b*TT*256;

  float4 v4 = *(float4*)(EXXTb + (long long)(TT-1)*256 + j*16 + 4*rgrp);
  *(float4*)&VL[j][4*rgrp] = v4;
  float mn_j = EXb[(TT-1)*16 + j];
  float logZ = out[KL_OFF + b];
  float klacc = 0.f;
  { // t = 999 kl term (diagonal-owner lanes)
    float jr = JrdB[(TT-1)*16 + j] + 0.5f, hv = hrB[(TT-1)*16 + j];
    float lo = (j & 1) ? v4.y : v4.x, hi = (j & 1) ? v4.w : v4.z;
    float vd = (j & 2) ? hi : lo;
    if (rgrp == (j >> 2)) klacc += -0.5f*jr*(vd + mn_j*mn_j) + hv*mn_j;
  }
  // prefetch t=998
  float4 pi4 = *(float4*)(EXXNTb + (long long)(TT-2)*256 + j*16 + 4*rgrp);
  float pm_j = EXb[(TT-2)*16 + j];
  float jr_j = JrdB[(TT-2)*16 + j], hr_j = hrB[(TT-2)*16 + j];
  WSYNC();

#pragma unroll 1
  for (int t = TT-2; t >= 0; --t){
    *(float4*)&PiL[j][4*rgrp] = pi4;
    float4 cpi = pi4;
    float cpm = pm_j, cjr = jr_j, chr = hr_j;
    if (t > 0){
      pi4  = *(float4*)(EXXNTb + (long long)(t-1)*256 + j*16 + 4*rgrp);
      pm_j = EXb[(t-1)*16 + j];
      jr_j = JrdB[(t-1)*16 + j]; hr_j = hrB[(t-1)*16 + j];
    }
    WSYNC();
    // G = Pi * AtL : G[i][j] = dot(Pi row i, AtLT row j)
    float Gq[4];
#pragma unroll
    for (int q = 0; q < 4; ++q){
      int i = 4*rgrp + q;
      float4 p0 = *(float4*)&PiL[i][0],  p1 = *(float4*)&PiL[i][4];
      float4 p2 = *(float4*)&PiL[i][8],  p3 = *(float4*)&PiL[i][12];
      Gq[q] = dot4(p0,atltr0) + dot4(p1,atltr1) + dot4(p2,atltr2) + dot4(p3,atltr3);
    }
#pragma unroll
    for (int q = 0; q < 4; ++q) GL[4*rgrp+q][j] = Gq[q];
    // m_t = pm + G mn
    float g0 = xor16sum(Gq[0]*mn_j), g1 = xor16sum(Gq[1]*mn_j);
    float g2 = xor16sum(Gq[2]*mn_j), g3 = xor16sum(Gq[3]*mn_j);
    float m_j = cpm + row2col(g0,g1,g2,g3, j);
    if (rgrp == 0) EXb[t*16 + j] = m_j;
    WSYNC();
    // C = G * V (V sym -> row.row)
    float4 vr0 = *(float4*)&VL[j][0],  vr1 = *(float4*)&VL[j][4];
    float4 vr2 = *(float4*)&VL[j][8],  vr3 = *(float4*)&VL[j][12];
    float4 gr0 = *(float4*)&GL[j][0],  gr1 = *(float4*)&GL[j][4];
    float4 gr2 = *(float4*)&GL[j][8],  gr3 = *(float4*)&GL[j][12];
    float Ctq[4];
#pragma unroll
    for (int q = 0; q < 4; ++q){
      int i = 4*rgrp + q;
      float4 w0 = *(float4*)&GL[i][0],  w1 = *(float4*)&GL[i][4];
      float4 w2 = *(float4*)&GL[i][8],  w3 = *(float4*)&GL[i][12];
      Ctq[q] = dot4(w0,vr0) + dot4(w1,vr1) + dot4(w2,vr2) + dot4(w3,vr3);
    }
#pragma unroll
    for (int q = 0; q < 4; ++q){
      int i = 4*rgrp + q;
      EXXNTb[(long long)t*256 + i*16 + j] = Ctq[q];
      WL[i][j] = Ctq[q];
    }
    WSYNC();
    // V_t = Pi + W G^T (row.row)
    float Vq[4];
#pragma unroll
    for (int q = 0; q < 4; ++q){
      int i = 4*rgrp + q;
      float4 w0 = *(float4*)&WL[i][0],  w1 = *(float4*)&WL[i][4];
      float4 w2 = *(float4*)&WL[i][8],  w3 = *(float4*)&WL[i][12];
      float pv = (q==0)?cpi.x:(q==1)?cpi.y:(q==2)?cpi.z:cpi.w;
      Vq[q] = pv + dot4(w0,gr0) + dot4(w1,gr1) + dot4(w2,gr2) + dot4(w3,gr3);
    }
    *(float4*)(EXXTb + (long long)t*256 + j*16 + 4*rgrp) = make_float4(Vq[0],Vq[1],Vq[2],Vq[3]);
#pragma unroll
    for (int q = 0; q < 4; ++q){
      int i = 4*rgrp + q;
      VL[i][j] = Vq[q];
      if (i == j) klacc += -0.5f*(cjr + 0.5f)*(Vq[q] + m_j*m_j) + chr*m_j;
    }
    mn_j = m_j;
    WSYNC();
  }
  klacc += __shfl_xor(klacc, 1);  klacc += __shfl_xor(klacc, 2);
  klacc += __shfl_xor(klacc, 4);  klacc += __shfl_xor(klacc, 8);
  klacc += __shfl_xor(klacc, 16); klacc += __shfl_xor(klacc, 32);
  if (tid == 0) out[KL_OFF + b] = klacc - logZ;
}

// =====================================================================
// Pass 3: parallel sampler prep. One wave per (b,t), t=0..998.
// Reads raw Vt,Ct,Vn,mt,mn. Computes K, L, e, u. Writes KT -> EXXNT[t],
// u -> z[b][t+1]. t==0 also writes x0 -> z[b][0].
// =====================================================================
__global__ __launch_bounds__(64) void lds_prep(float* __restrict__ out)
{
  const int t = blockIdx.x;   // 0..998
  const int b = blockIdx.y;
  const int tid = threadIdx.x;
  const int j = tid & 15, rgrp = tid >> 4;

  __shared__ __align__(16) float CtTL[16][ST], KTL[16][ST];

  float* EXXNTb = out + EXXNT_OFF + (long long)b*(TT-1)*256;
  float* EXb    = out + EX_OFF    + (long long)b*TT*16;
  float* EXXTb  = out + EXXT_OFF  + (long long)b*TT*256;
  float* zB     = out + Z_OFF     + (long long)b*TT*16;

  float4 vt4 = *(float4*)(EXXTb + (long long)t*256 + j*16 + 4*rgrp);     // Vt rows (sym)
  float aM[4] = {vt4.x, vt4.y, vt4.z, vt4.w};
  float aS[4];
#pragma unroll
  for (int q = 0; q < 4; ++q) aS[q] = EXXNTb[(long long)t*256 + (4*rgrp+q)*16 + j]; // Ct rows
  *(float4*)&CtTL[j][4*rgrp] = make_float4(aS[0],aS[1],aS[2],aS[3]);     // CtT rows
  float dummy = 0.f;
  sweep16<true,false>(aM, aS, rgrp, j, dummy);                            // aS = K rows
  *(float4*)(EXXNTb + (long long)t*256 + j*16 + 4*rgrp) = make_float4(aS[0],aS[1],aS[2],aS[3]); // KT
  *(float4*)&KTL[j][4*rgrp] = make_float4(aS[0],aS[1],aS[2],aS[3]);       // KT rows
  WSYNC();

  float4 vn4 = *(float4*)(EXXTb + (long long)(t+1)*256 + j*16 + 4*rgrp);  // Vn rows (sym)
  float cv[4];
#pragma unroll
  for (int q = 0; q < 4; ++q){
    int i = 4*rgrp + q;
    float4 c0 = *(float4*)&CtTL[i][0],  c1 = *(float4*)&CtTL[i][4];
    float4 c2 = *(float4*)&CtTL[i][8],  c3 = *(float4*)&CtTL[i][12];
    float4 k0 = *(float4*)&KTL[j][0],   k1 = *(float4*)&KTL[j][4];
    float4 k2 = *(float4*)&KTL[j][8],   k3 = *(float4*)&KTL[j][12];
    float s = dot4(c0,k0) + dot4(c1,k1) + dot4(c2,k2) + dot4(c3,k3);
    float vn = (q==0)?vn4.x:(q==1)?vn4.y:(q==2)?vn4.z:vn4.w;
    cv[q] = vn - s + ((i==j) ? 1e-6f : 0.f);
  }
  chol16r(cv, rgrp, j);

  unsigned kk0, kk1; batch_key(b, kk0, kk1);
  float e_j  = eps_val(kk0, kk1, (t+1)*16 + j);
  float mt_j = EXb[t*16 + j];
  float mn_j = EXb[(t+1)*16 + j];

  float pu[4];
#pragma unroll
  for (int q = 0; q < 4; ++q){
    int i = 4*rgrp + q;
    float kt = KTL[i][j];                         // KT[i][j]
    pu[q] = ((j <= i) ? cv[q]*e_j : 0.f) - kt*mt_j;
  }
#pragma unroll
  for (int q = 0; q < 4; ++q) pu[q] = xor16sum(pu[q]);
  float u_j = mn_j + row2col(pu[0],pu[1],pu[2],pu[3], j);
  if (rgrp == 0) zB[(t+1)*16 + j] = u_j;

  if (t == 0){
    float cv0[4] = {vt4.x, vt4.y, vt4.z, vt4.w};
#pragma unroll
    for (int q = 0; q < 4; ++q){ if (4*rgrp+q == j) cv0[q] += 1e-6f; }
    chol16r(cv0, rgrp, j);
    float e0 = eps_val(kk0, kk1, j);
    float p[4];
#pragma unroll
    for (int q = 0; q < 4; ++q){ int i = 4*rgrp + q; p[q] = (j <= i) ? cv0[q]*e0 : 0.f; }
#pragma unroll
    for (int q = 0; q < 4; ++q) p[q] = xor16sum(p[q]);
    float x0_j = mt_j + row2col(p[0],p[1],p[2],p[3], j);
    if (rgrp == 0) zB[j] = x0_j;
  }
}

// =====================================================================
// Pass 4: serial z-chain. One wave per batch. z_{t+1} = K^T z_t + u.
// Depth-8 register prefetch ring for KT / u.
// =====================================================================
__global__ __launch_bounds__(64) void lds_chain(float* __restrict__ out)
{
  const int b = blockIdx.x, tid = threadIdx.x;
  const int j = tid & 15, rgrp = tid >> 4;
  float* zB  = out + Z_OFF + (long long)b*TT*16;
  float* KTb = out + EXXNT_OFF + (long long)b*(TT-1)*256;

  float zj = zB[j];
  float zc0 = __shfl(zj, 4*rgrp+0), zc1 = __shfl(zj, 4*rgrp+1);
  float zc2 = __shfl(zj, 4*rgrp+2), zc3 = __shfl(zj, 4*rgrp+3);

  float4 kb[8]; float ub[8];
#pragma unroll
  for (int c = 0; c < 8; ++c){
    kb[c] = *(float4*)(KTb + (long long)c*256 + j*16 + 4*rgrp);
    ub[c] = zB[(c+1)*16 + j];
  }

#pragma unroll 1
  for (int t0 = 0; t0 < TT-1; t0 += 8){
#define CSTEP(c) { int t = t0 + (c); if (t < TT-1){                                     \
      float4 k4 = kb[c];                                                                \
      float p = k4.x*zc0 + k4.y*zc1 + k4.z*zc2 + k4.w*zc3;                              \
      p += __shfl_xor(p, 16); p += __shfl_xor(p, 32);                                   \
      float zn = p + ub[c];                                                             \
      if (rgrp == 0) zB[(t+1)*16 + j] = zn;                                             \
      int tn = t + 8;                                                                   \
      if (tn < TT-1){ kb[c] = *(float4*)(KTb + (long long)tn*256 + j*16 + 4*rgrp);      \
                      ub[c] = zB[(tn+1)*16 + j]; }                                      \
      zj = zn;                                                                          \
      zc0 = __shfl(zj, 4*rgrp+0); zc1 = __shfl(zj, 4*rgrp+1);                           \
      zc2 = __shfl(zj, 4*rgrp+2); zc3 = __shfl(zj, 4*rgrp+3); } }
    CSTEP(0) CSTEP(1) CSTEP(2) CSTEP(3) CSTEP(4) CSTEP(5) CSTEP(6) CSTEP(7)
#undef CSTEP
  }
}

// =====================================================================
// Pass 5: parallel moment finalization. One wave per (b,t), t=0..999.
// EXXT[t] = Vt + mt mt^T ; EXXNT[t] = Vt*K + mt mn^T (Ct recomputed from KT).
// =====================================================================
__global__ __launch_bounds__(64) void lds_mom(float* __restrict__ out)
{
  const int t = blockIdx.x;   // 0..999
  const int b = blockIdx.y;
  const int tid = threadIdx.x;
  const int j = tid & 15, rgrp = tid >> 4;

  __shared__ __align__(16) float VtL[16][ST], KTL[16][ST];

  float* EXXNTb = out + EXXNT_OFF + (long long)b*(TT-1)*256;
  float* EXb    = out + EX_OFF    + (long long)b*TT*16;
  float* EXXTb  = out + EXXT_OFF  + (long long)b*TT*256;

  float4 vt4 = *(float4*)(EXXTb + (long long)t*256 + j*16 + 4*rgrp);   // Vt[j][4rgrp+c]
  float mt_j = EXb[t*16 + j];
  float mtr[4];
#pragma unroll
  for (int q = 0; q < 4; ++q) mtr[q] = EXb[t*16 + 4*rgrp + q];

  float4 f4;
  f4.x = vt4.x + mt_j*mtr[0]; f4.y = vt4.y + mt_j*mtr[1];
  f4.z = vt4.z + mt_j*mtr[2]; f4.w = vt4.w + mt_j*mtr[3];

  if (t == TT-1){
    *(float4*)(EXXTb + (long long)t*256 + j*16 + 4*rgrp) = f4;
    return;
  }
  float4 kt4 = *(float4*)(EXXNTb + (long long)t*256 + j*16 + 4*rgrp);  // KT[j][4rgrp+c]
  *(float4*)&VtL[j][4*rgrp] = vt4;
  *(float4*)&KTL[j][4*rgrp] = kt4;
  *(float4*)(EXXTb + (long long)t*256 + j*16 + 4*rgrp) = f4;
  WSYNC();

  float mn_j = EXb[(t+1)*16 + j];
  float4 k0 = *(float4*)&KTL[j][0],  k1 = *(float4*)&KTL[j][4];
  float4 k2 = *(float4*)&KTL[j][8],  k3 = *(float4*)&KTL[j][12];
#pragma unroll
  for (int q = 0; q < 4; ++q){
    int i = 4*rgrp + q;
    float4 v0 = *(float4*)&VtL[i][0],  v1 = *(float4*)&VtL[i][4];
    float4 v2 = *(float4*)&VtL[i][8],  v3 = *(float4*)&VtL[i][12];
    float ct = dot4(v0,k0) + dot4(v1,k1) + dot4(v2,k2) + dot4(v3,k3);
    EXXNTb[(long long)t*256 + i*16 + j] = ct + mtr[q]*mn_j;
  }
}

// =====================================================================
extern "C" void kernel_launch(void* const* d_in, const int* in_sizes, int n_in,
                              void* d_out, int out_size, void* d_ws, size_t ws_size,
                              hipStream_t stream) {
  (void)in_sizes; (void)n_in; (void)d_ws; (void)ws_size; (void)out_size;
  const float* Jrd  = (const float*)d_in[0];
  const float* hr   = (const float*)d_in[1];
  const float* loc  = (const float*)d_in[2];
  const float* Taup = (const float*)d_in[3];
  const float* Lamp = (const float*)d_in[4];
  const float* X    = (const float*)d_in[5];
  float* out = (float*)d_out;

  lds_fwd<<<64, 64, 0, stream>>>(Jrd, hr, loc, Taup, Lamp, X, out);
  lds_bwd<<<64, 64, 0, stream>>>(Jrd, hr, Lamp, X, out);
  lds_prep<<<dim3(TT-1, 64), 64, 0, stream>>>(out);
  lds_chain<<<64, 64, 0, stream>>>(out);
  lds_mom<<<dim3(TT, 64), 64, 0, stream>>>(out);
}

// Round 3
// 926.157 us; speedup vs baseline: 15.8680x; 5.3189x over previous
//
#include <hip/hip_runtime.h>

// Problem constants
constexpr int TT   = 1000;
constexpr int ST   = 20;   // padded LDS row stride
constexpr int NC   = 32;   // chunks per batch (time direction)
constexpr int CL   = 32;   // steps per chunk  (NC*CL >= TT-1)
constexpr int WARM = 64;   // warm-up steps (contraction ~0.5-0.75/step -> <1e-8 residual)
static_assert(NC * CL >= TT - 1, "chunk cover");

// d_out layout (floats): z | kl | EXXT | EX | EXXNT
constexpr long long Z_OFF     = 0;
constexpr long long KL_OFF    = 1024000;
constexpr long long EXXT_OFF  = 1024064;
constexpr long long EX_OFF    = 17408064;
constexpr long long EXXNT_OFF = 18432064;

#define WSYNC() { __builtin_amdgcn_wave_barrier(); __builtin_amdgcn_sched_barrier(0); }

struct CT { static constexpr bool value = true;  };
struct CF { static constexpr bool value = false; };

// ---------- helpers ----------
__device__ __forceinline__ float dot4(float4 a, float4 b){
  return a.x*b.x + a.y*b.y + a.z*b.z + a.w*b.w;
}

// DPP-based sum over each 16-lane j-group (VALU only, no DS latency)
template<int CTRL>
__device__ __forceinline__ float dppadd(float v){
  int x = __builtin_amdgcn_update_dpp(0, __float_as_int(v), CTRL, 0xF, 0xF, false);
  return v + __int_as_float(x);
}
__device__ __forceinline__ float xor16sum(float v){
  v = dppadd<0xB1>(v);   // quad_perm(1,0,3,2) : ^1
  v = dppadd<0x4E>(v);   // quad_perm(2,3,0,1) : ^2
  v = dppadd<0x124>(v);  // row_ror:4
  v = dppadd<0x128>(v);  // row_ror:8
  return v;
}

// rows r0..r3 hold values for rows 4*rgrp+q, replicated within each 16-lane group.
__device__ __forceinline__ float row2col(float r0, float r1, float r2, float r3, int j){
  int s = (j >> 2) << 4;
  float t0 = __shfl(r0, s), t1 = __shfl(r1, s), t2 = __shfl(r2, s), t3 = __shfl(r3, s);
  float lo = (j & 1) ? t1 : t0, hi = (j & 1) ? t3 : t2;
  return (j & 2) ? hi : lo;
}

// In-place Gauss-Jordan sweep: aM -> inv(aM); aS -> inv(M)*S. SPD, no pivoting.
template<bool WITH_S, bool LOGDET>
__device__ __forceinline__ void sweep16(float* aM, float* aS, const int rgrp, const int j, float& ld){
#pragma unroll
  for (int k = 0; k < 16; ++k){
    const int kg = k >> 2, kq = k & 3;
    const int psrc = (kg << 4) | j;
    float prM = __shfl(aM[kq], psrc);
    float prS = WITH_S ? __shfl(aS[kq], psrc) : 0.f;
    float piv = __shfl(aM[kq], (kg << 4) | k);
    float f0 = __shfl(aM[0], (rgrp << 4) | k);
    float f1 = __shfl(aM[1], (rgrp << 4) | k);
    float f2 = __shfl(aM[2], (rgrp << 4) | k);
    float f3 = __shfl(aM[3], (rgrp << 4) | k);
    float invp = __builtin_amdgcn_rcpf(piv);
    if (LOGDET) ld += __logf(piv);
    const bool pivCol = (j == k);
    const bool pivG   = (rgrp == kg);
    float fi[4] = {f0*invp, f1*invp, f2*invp, f3*invp};
#pragma unroll
    for (int q = 0; q < 4; ++q){
      const bool isPivRow = pivG && (q == kq);
      float nM = aM[q] - fi[q]*prM;
      if (pivCol)   nM = -fi[q];
      if (isPivRow) nM = pivCol ? invp : prM*invp;
      aM[q] = nM;
      if (WITH_S){
        float nS = aS[q] - fi[q]*prS;
        if (isPivRow) nS = prS*invp;
        aS[q] = nS;
      }
    }
  }
}

// Register-resident Cholesky (lower). cv[q] = A[4*rgrp+q][j]; L in lower incl diag on exit.
__device__ __forceinline__ void chol16r(float* cv, const int rgrp, const int j){
#pragma unroll
  for (int k = 0; k < 16; ++k){
    const int kg = k >> 2, kq = k & 3;
    float piv = __shfl(cv[kq], (kg << 4) | k);
    float s   = sqrtf(piv);
    float inv = __builtin_amdgcn_rcpf(s);
    const int srcjk = ((j >> 2) << 4) | k;
    float t0 = __shfl(cv[0], srcjk), t1 = __shfl(cv[1], srcjk);
    float t2 = __shfl(cv[2], srcjk), t3 = __shfl(cv[3], srcjk);
    float lo = (j & 1) ? t1 : t0, hi = (j & 1) ? t3 : t2;
    float Ljk = ((j & 2) ? hi : lo) * inv;
    const int srcik = (rgrp << 4) | k;
    float a0 = __shfl(cv[0], srcik), a1 = __shfl(cv[1], srcik);
    float a2 = __shfl(cv[2], srcik), a3 = __shfl(cv[3], srcik);
    float Lik[4] = {a0*inv, a1*inv, a2*inv, a3*inv};
#pragma unroll
    for (int q = 0; q < 4; ++q){
      int iq = 4*rgrp + q;
      float v = cv[q];
      if (j == k)                 v = (iq > k) ? Lik[q] : ((iq == k) ? s : v);
      else if (j > k && iq > k)   v = v - Lik[q]*Ljk;
      cv[q] = v;
    }
  }
}

// ---------- threefry2x32 (JAX-exact) ----------
__device__ __forceinline__ unsigned rotl32(unsigned x, int r){ return (x << r) | (x >> (32 - r)); }

__device__ void threefry2x32(unsigned k0, unsigned k1, unsigned c0, unsigned c1,
                             unsigned &o0, unsigned &o1){
  unsigned ks2 = k0 ^ k1 ^ 0x1BD11BDAu;
  unsigned x0 = c0 + k0, x1 = c1 + k1;
#define TF_R(r) { x0 += x1; x1 = rotl32(x1, r); x1 ^= x0; }
  TF_R(13) TF_R(15) TF_R(26) TF_R(6)
  x0 += k1;  x1 += ks2 + 1u;
  TF_R(17) TF_R(29) TF_R(16) TF_R(24)
  x0 += ks2; x1 += k0 + 2u;
  TF_R(13) TF_R(15) TF_R(26) TF_R(6)
  x0 += k0;  x1 += k1 + 3u;
  TF_R(17) TF_R(29) TF_R(16) TF_R(24)
  x0 += k1;  x1 += ks2 + 4u;
  TF_R(13) TF_R(15) TF_R(26) TF_R(6)
  x0 += ks2; x1 += k0 + 5u;
#undef TF_R
  o0 = x0; o1 = x1;
}

__device__ float erfinv32(float x){
  float w = -log1pf(-x*x);
  float p;
  if (w < 5.0f) {
    w -= 2.5f;
    p =  2.81022636e-08f;
    p = fmaf(p, w,  3.43273939e-07f);
    p = fmaf(p, w, -3.5233877e-06f);
    p = fmaf(p, w, -4.39150654e-06f);
    p = fmaf(p, w,  0.00021858087f);
    p = fmaf(p, w, -0.00125372503f);
    p = fmaf(p, w, -0.00417768164f);
    p = fmaf(p, w,  0.246640727f);
    p = fmaf(p, w,  1.50140941f);
  } else {
    w = sqrtf(w) - 3.0f;
    p = -0.000200214257f;
    p = fmaf(p, w,  0.000100950558f);
    p = fmaf(p, w,  0.00134934322f);
    p = fmaf(p, w, -0.00367342844f);
    p = fmaf(p, w,  0.00573950773f);
    p = fmaf(p, w, -0.0076224613f);
    p = fmaf(p, w,  0.00943887047f);
    p = fmaf(p, w,  1.00167406f);
    p = fmaf(p, w,  2.83297682f);
  }
  return p * x;
}

__device__ __forceinline__ float bits_to_normal(unsigned b){
  float f = __uint_as_float((b >> 9) | 0x3f800000u) - 1.0f;
  const float lo = -0.99999994f;
  float u = fmaxf(lo, f * 2.0f + lo);
  return 1.41421356f * erfinv32(u);
}

__device__ float eps_val(unsigned k0, unsigned k1, int p){
  unsigned o0, o1;
  if (p < 8000) { threefry2x32(k0,k1,(unsigned)p,(unsigned)(p+8000),o0,o1); return bits_to_normal(o0); }
  threefry2x32(k0,k1,(unsigned)(p-8000),(unsigned)p,o0,o1); return bits_to_normal(o1);
}

__device__ void batch_key(int b, unsigned &k0, unsigned &k1){
  unsigned a0, a1, d;
  if (b < 32) {
    threefry2x32(0u,42u, (unsigned)(2*b),   (unsigned)(2*b+64), a0, d);
    threefry2x32(0u,42u, (unsigned)(2*b+1), (unsigned)(2*b+65), a1, d);
  } else {
    threefry2x32(0u,42u, (unsigned)(2*b-64), (unsigned)(2*b),   d, a0);
    threefry2x32(0u,42u, (unsigned)(2*b-63), (unsigned)(2*b+1), d, a1);
  }
  k0 = a0; k1 = a1;
}

// =====================================================================
__global__ void init_kl(float* __restrict__ out){
  out[KL_OFF + threadIdx.x] = 0.f;
}

// =====================================================================
// Pass 1: forward information filter, chunked over time with warm-up.
// grid (NC, 64); block = 1 wave. Chunk c handles steps [c*CL, min(c*CL+CL,999)).
// =====================================================================
__global__ __launch_bounds__(64) void lds_fwd(
    const float* __restrict__ Jrd, const float* __restrict__ hr,
    const float* __restrict__ loc, const float* __restrict__ Taup,
    const float* __restrict__ Lamp, const float* __restrict__ X,
    float* __restrict__ out)
{
  const int c = blockIdx.x, b = blockIdx.y;
  const int tid = threadIdx.x;
  const int j = tid & 15, rgrp = tid >> 4;

  __shared__ __align__(16) float sA[16][ST], sTp[16][ST], sLp[16][ST];
  __shared__ __align__(16) float sTau[16][ST], sLam[16][ST], sAtL[16][ST], sAtLT[16][ST];
  __shared__ __align__(16) float STL[16][ST];
  __shared__ __align__(16) float mL[16];
  __shared__ float vecb[16], vloc[16];

  // ---- setup ----
#pragma unroll
  for (int q = 0; q < 4; ++q){
    int i = 4*rgrp + q;
    sTp[i][j] = Taup[i*16 + j];
    sLp[i][j] = Lamp[i*16 + j];
    sA[i][j]  = X[i*17 + j];
  }
  if (tid < 16){ vloc[tid] = loc[tid]; vecb[tid] = X[tid*17 + 16]; }
  __syncthreads();

#pragma unroll
  for (int q = 0; q < 4; ++q){
    int i = 4*rgrp + q;
    float s0 = 0.f, s1 = 0.f;
    for (int k = 0; k < 16; ++k){ s0 += sTp[i][k]*sTp[j][k]; s1 += sLp[i][k]*sLp[j][k]; }
    sTau[i][j] = s0 + (i==j ? 1e-8f : 0.f);
    sLam[i][j] = s1 + (i==j ? 1e-8f : 0.f);
  }
  __syncthreads();

  float atlrow[4];
#pragma unroll
  for (int q = 0; q < 4; ++q){
    int i = 4*rgrp + q;
    float s = 0.f;
    for (int k = 0; k < 16; ++k) s += sA[k][i]*sLam[k][j];
    atlrow[q] = s;
  }
  __syncthreads();
#pragma unroll
  for (int q = 0; q < 4; ++q){
    int i = 4*rgrp + q;
    sAtL[i][j] = atlrow[q];
    sAtLT[j][i] = atlrow[q];
  }
  __syncthreads();

  float atla[4];
#pragma unroll
  for (int q = 0; q < 4; ++q){
    int i = 4*rgrp + q;
    float s = 0.f;
    for (int k = 0; k < 16; ++k) s += sAtL[i][k]*sA[k][j];
    atla[q] = s;
  }

  float b_j = vecb[j], loc_j = vloc[j];
  float pA[4], pL[4], pT[4];
#pragma unroll
  for (int q = 0; q < 4; ++q){
    int i = 4*rgrp + q;
    pA[q] = atlrow[q]*b_j;
    pL[q] = sLam[i][j]*b_j;
    pT[q] = sTau[i][j]*loc_j;
  }
#pragma unroll
  for (int q = 0; q < 4; ++q){ pA[q] = xor16sum(pA[q]); pL[q] = xor16sum(pL[q]); pT[q] = xor16sum(pT[q]); }
  float AtLb_j = row2col(pA[0],pA[1],pA[2],pA[3], j);
  float Lb_j   = row2col(pL[0],pL[1],pL[2],pL[3], j);
  float tmu_j  = row2col(pT[0],pT[1],pT[2],pT[3], j);

  float ld_lam = 0.f, ld_tau = 0.f;
  {
    float r[4], d[4];
#pragma unroll
    for (int q = 0; q < 4; ++q){ r[q] = sLam[4*rgrp+q][j]; d[q] = 0.f; }
    sweep16<false,true>(r, d, rgrp, j, ld_lam);
#pragma unroll
    for (int q = 0; q < 4; ++q){ r[q] = sTau[4*rgrp+q][j]; }
    sweep16<false,true>(r, d, rgrp, j, ld_tau);
  }
  float dBL = xor16sum(b_j*Lb_j);
  float dLT = xor16sum(loc_j*tmu_j);
  const float trans_const = -0.5f*dBL + 0.5f*ld_lam;
  const float init_const  = -0.5f*dLT + 0.5f*ld_tau;

  const float* JrdB = Jrd + (long long)b*TT*16;
  const float* hrB  = hr  + (long long)b*TT*16;
  float* EXXNTb = out + EXXNT_OFF + (long long)b*(TT-1)*256;
  float* EXb    = out + EX_OFF    + (long long)b*TT*16;
  float* EXXTb  = out + EXXT_OFF  + (long long)b*TT*256;

  // ---- chunk bounds ----
  const int s0 = c * CL;
  const int s1 = min(s0 + CL, TT - 1);
  const int t0 = max(0, s0 - WARM);

  float lam4[4], fj[4];
#pragma unroll
  for (int q = 0; q < 4; ++q){
    int i = 4*rgrp + q;
    lam4[q] = sLam[i][j];
    // init at t0: exact prior when t0==0, warm-start guess otherwise (same formula)
    fj[q]   = sTau[i][j] + ((i==j) ? (JrdB[t0*16 + j] + 0.5f) : 0.f);
  }
  float fh_j = tmu_j + hrB[t0*16 + j];
  float jr_nx = JrdB[(t0+1)*16 + j], hr_nx = hrB[(t0+1)*16 + j];
  float lz = 0.f;

  auto step = [&](int t, auto fullc){
    constexpr bool FULL = decltype(fullc)::value;
    float m_j = fh_j - AtLb_j;
    float aM[4], aS[4];
#pragma unroll
    for (int q = 0; q < 4; ++q){ aM[q] = fj[q] + atla[q]; aS[q] = atlrow[q]; }
    float ld = 0.f;
    sweep16<true, FULL>(aM, aS, rgrp, j, ld);

    if (FULL)
      *(float4*)(EXXNTb + (long long)t*256 + j*16 + 4*rgrp) = make_float4(aM[0],aM[1],aM[2],aM[3]);

    float p0 = xor16sum(aM[0]*m_j), p1 = xor16sum(aM[1]*m_j);
    float p2 = xor16sum(aM[2]*m_j), p3 = xor16sum(aM[3]*m_j);
    float mim_j = row2col(p0,p1,p2,p3, j);
    if (FULL){
      if (rgrp == 0) EXb[t*16 + j] = mim_j;
      float dm = xor16sum(m_j * mim_j);
      lz += 0.5f*dm - 0.5f*ld + trans_const;
    }

    *(float4*)&STL[j][4*rgrp] = make_float4(aS[0],aS[1],aS[2],aS[3]);
    if (rgrp == 0) mL[j] = mim_j;
    WSYNC();

    float4 st0 = *(float4*)&STL[j][0],  st1 = *(float4*)&STL[j][4];
    float4 st2 = *(float4*)&STL[j][8],  st3 = *(float4*)&STL[j][12];
    float4 ml0 = *(float4*)&mL[0], ml1 = *(float4*)&mL[4];
    float4 ml2 = *(float4*)&mL[8], ml3 = *(float4*)&mL[12];

    float jr_c = jr_nx, hr_c = hr_nx;
    if (t + 2 < TT){ jr_nx = JrdB[(t+2)*16 + j]; hr_nx = hrB[(t+2)*16 + j]; }

    float Cq[4], ach[4];
#pragma unroll
    for (int q = 0; q < 4; ++q){
      int i = 4*rgrp + q;
      float4 a0 = *(float4*)&sAtLT[i][0],  a1 = *(float4*)&sAtLT[i][4];
      float4 a2 = *(float4*)&sAtLT[i][8],  a3 = *(float4*)&sAtLT[i][12];
      Cq[q]  = dot4(a0,st0) + dot4(a1,st1) + dot4(a2,st2) + dot4(a3,st3);
      ach[q] = dot4(a0,ml0) + dot4(a1,ml1) + dot4(a2,ml2) + dot4(a3,ml3);
    }
#pragma unroll
    for (int q = 0; q < 4; ++q){
      int i = 4*rgrp + q;
      fj[q] = lam4[q] - Cq[q] + ((i==j) ? (jr_c + 0.5f) : 0.f);
    }
    float ach_j = row2col(ach[0],ach[1],ach[2],ach[3], j);
    fh_j = Lb_j + ach_j + hr_c;
    WSYNC();
  };

#pragma unroll 1
  for (int t = t0; t < s0; ++t) step(t, CF{});
#pragma unroll 1
  for (int t = s0; t < s1; ++t) step(t, CT{});

  if (c == NC-1){
    // tail: VT = inv(fJT), mT, tail logZ terms
    float aM[4], d[4];
#pragma unroll
    for (int q = 0; q < 4; ++q){ aM[q] = fj[q]; d[q] = 0.f; }
    float ldT = 0.f;
    sweep16<false,true>(aM, d, rgrp, j, ldT);
    *(float4*)(EXXTb + (long long)(TT-1)*256 + j*16 + 4*rgrp) = make_float4(aM[0],aM[1],aM[2],aM[3]);
    float p0 = xor16sum(aM[0]*fh_j), p1 = xor16sum(aM[1]*fh_j);
    float p2 = xor16sum(aM[2]*fh_j), p3 = xor16sum(aM[3]*fh_j);
    float mT_j = row2col(p0,p1,p2,p3, j);
    if (rgrp == 0) EXb[(TT-1)*16 + j] = mT_j;
    float dfm = xor16sum(fh_j * mT_j);
    lz += 0.5f*dfm - 0.5f*ldT;
  }
  if (c == 0) lz += init_const;
  if (tid == 0) atomicAdd(out + KL_OFF + b, lz);
}

// =====================================================================
// Backward smoother step (shared by warm/main kernels)
// =====================================================================
template<bool FULL>
__device__ __forceinline__ void bwd_step(
    int t, int lo, int rgrp, int j,
    float (*PiL)[ST], float (*GL)[ST], float (*WL)[ST], float (*VL)[ST],
    float4 atltr0, float4 atltr1, float4 atltr2, float4 atltr3,
    float4& pi4, float& pm_j, float& jr_j, float& hr_j,
    float& mn_j, float& klacc,
    const float* JrdB, const float* hrB,
    float* EXXNTb, float* EXb, float* EXXTb)
{
  *(float4*)&PiL[j][4*rgrp] = pi4;
  float4 cpi = pi4; float cpm = pm_j, cjr = jr_j, chr = hr_j;
  if (t > lo){
    pi4  = *(const float4*)(EXXNTb + (long long)(t-1)*256 + j*16 + 4*rgrp);
    pm_j = EXb[(t-1)*16 + j];
    if (FULL){ jr_j = JrdB[(t-1)*16 + j]; hr_j = hrB[(t-1)*16 + j]; }
  }
  WSYNC();
  float Gq[4];
#pragma unroll
  for (int q = 0; q < 4; ++q){
    int i = 4*rgrp + q;
    float4 p0 = *(float4*)&PiL[i][0],  p1 = *(float4*)&PiL[i][4];
    float4 p2 = *(float4*)&PiL[i][8],  p3 = *(float4*)&PiL[i][12];
    Gq[q] = dot4(p0,atltr0) + dot4(p1,atltr1) + dot4(p2,atltr2) + dot4(p3,atltr3);
  }
#pragma unroll
  for (int q = 0; q < 4; ++q) GL[4*rgrp+q][j] = Gq[q];
  float g0 = xor16sum(Gq[0]*mn_j), g1 = xor16sum(Gq[1]*mn_j);
  float g2 = xor16sum(Gq[2]*mn_j), g3 = xor16sum(Gq[3]*mn_j);
  float m_j = cpm + row2col(g0,g1,g2,g3, j);
  if (FULL && rgrp == 0) EXb[t*16 + j] = m_j;
  WSYNC();
  float4 vr0 = *(float4*)&VL[j][0],  vr1 = *(float4*)&VL[j][4];
  float4 vr2 = *(float4*)&VL[j][8],  vr3 = *(float4*)&VL[j][12];
  float4 gr0 = *(float4*)&GL[j][0],  gr1 = *(float4*)&GL[j][4];
  float4 gr2 = *(float4*)&GL[j][8],  gr3 = *(float4*)&GL[j][12];
  float Ctq[4];
#pragma unroll
  for (int q = 0; q < 4; ++q){
    int i = 4*rgrp + q;
    float4 w0 = *(float4*)&GL[i][0],  w1 = *(float4*)&GL[i][4];
    float4 w2 = *(float4*)&GL[i][8],  w3 = *(float4*)&GL[i][12];
    Ctq[q] = dot4(w0,vr0) + dot4(w1,vr1) + dot4(w2,vr2) + dot4(w3,vr3);
  }
#pragma unroll
  for (int q = 0; q < 4; ++q){
    int i = 4*rgrp + q;
    if (FULL) EXXNTb[(long long)t*256 + i*16 + j] = Ctq[q];
    WL[i][j] = Ctq[q];
  }
  WSYNC();
  float Vq[4];
#pragma unroll
  for (int q = 0; q < 4; ++q){
    int i = 4*rgrp + q;
    float4 w0 = *(float4*)&WL[i][0],  w1 = *(float4*)&WL[i][4];
    float4 w2 = *(float4*)&WL[i][8],  w3 = *(float4*)&WL[i][12];
    float pv = (q==0)?cpi.x:(q==1)?cpi.y:(q==2)?cpi.z:cpi.w;
    Vq[q] = pv + dot4(w0,gr0) + dot4(w1,gr1) + dot4(w2,gr2) + dot4(w3,gr3);
  }
  if (FULL)
    *(float4*)(EXXTb + (long long)t*256 + j*16 + 4*rgrp) = make_float4(Vq[0],Vq[1],Vq[2],Vq[3]);
#pragma unroll
  for (int q = 0; q < 4; ++q){
    int i = 4*rgrp + q;
    VL[i][j] = Vq[q];
    if (FULL && i == j) klacc += -0.5f*(cjr + 0.5f)*(Vq[q] + m_j*m_j) + chr*m_j;
  }
  mn_j = m_j;
  WSYNC();
}

__device__ __forceinline__ void bwd_setup(
    const float* Lamp, const float* X, int rgrp, int j,
    float (*sA)[ST], float (*sLp)[ST], float (*sLam)[ST], float (*sAtLT)[ST],
    float4& a0, float4& a1, float4& a2, float4& a3)
{
#pragma unroll
  for (int q = 0; q < 4; ++q){
    int i = 4*rgrp + q;
    sLp[i][j] = Lamp[i*16 + j];
    sA[i][j]  = X[i*17 + j];
  }
  __syncthreads();
#pragma unroll
  for (int q = 0; q < 4; ++q){
    int i = 4*rgrp + q;
    float s = 0.f;
    for (int k = 0; k < 16; ++k) s += sLp[i][k]*sLp[j][k];
    sLam[i][j] = s + (i==j ? 1e-8f : 0.f);
  }
  __syncthreads();
#pragma unroll
  for (int q = 0; q < 4; ++q){
    int i = 4*rgrp + q;
    float s = 0.f;
    for (int k = 0; k < 16; ++k) s += sA[k][i]*sLam[k][j];   // AtL[i][j]
    sAtLT[j][i] = s;
  }
  __syncthreads();
  a0 = *(float4*)&sAtLT[j][0];  a1 = *(float4*)&sAtLT[j][4];
  a2 = *(float4*)&sAtLT[j][8];  a3 = *(float4*)&sAtLT[j][12];
}

// =====================================================================
// Pass 2a: bwd warm — compute each chunk's entry state (V,m) at t=(c+1)*CL.
// Reads only fwd outputs (no writes to them); stores entry into z-region scratch.
// Chunk 0's lane 0 also flips kl slot to -logZ.
// =====================================================================
__global__ __launch_bounds__(64) void lds_bwd_warm(
    const float* __restrict__ Lamp, const float* __restrict__ X,
    float* __restrict__ out)
{
  const int c = blockIdx.x, b = blockIdx.y;
  const int tid = threadIdx.x;
  const int j = tid & 15, rgrp = tid >> 4;

  __shared__ __align__(16) float sA[16][ST], sLp[16][ST], sLam[16][ST], sAtLT[16][ST];
  __shared__ __align__(16) float PiL[16][ST], GL[16][ST], WL[16][ST], VL[16][ST];

  float4 atltr0, atltr1, atltr2, atltr3;
  bwd_setup(Lamp, X, rgrp, j, sA, sLp, sLam, sAtLT, atltr0, atltr1, atltr2, atltr3);

  float* EXXNTb = out + EXXNT_OFF + (long long)b*(TT-1)*256;
  float* EXb    = out + EX_OFF    + (long long)b*TT*16;
  float* EXXTb  = out + EXXT_OFF  + (long long)b*TT*256;
  float* zscr   = out + Z_OFF + (long long)(b*NC + c)*272;

  const int e  = (c+1)*CL;                   // want state entering step e-1
  const int ts = min(e - 1 + WARM, TT-2);    // first warm step processed

  float mn_j;
  if (ts == TT-2){  // exact terminal init
    float4 v4 = *(const float4*)(EXXTb + (long long)(TT-1)*256 + j*16 + 4*rgrp);
    *(float4*)&VL[j][4*rgrp] = v4;
    mn_j = EXb[(TT-1)*16 + j];
  } else {          // warm-start guess: filtered quantities
    float4 v4 = *(const float4*)(EXXNTb + (long long)(ts+1)*256 + j*16 + 4*rgrp);
    *(float4*)&VL[j][4*rgrp] = v4;
    mn_j = EXb[(ts+1)*16 + j];
  }
  float4 pi4 = make_float4(0,0,0,0);
  float pm_j = 0.f, jr_j = 0.f, hr_j = 0.f, klacc = 0.f;
  if (ts >= e){
    pi4  = *(const float4*)(EXXNTb + (long long)ts*256 + j*16 + 4*rgrp);
    pm_j = EXb[ts*16 + j];
  }
  WSYNC();

#pragma unroll 1
  for (int t = ts; t >= e; --t)
    bwd_step<false>(t, e, rgrp, j, PiL, GL, WL, VL,
                    atltr0, atltr1, atltr2, atltr3,
                    pi4, pm_j, jr_j, hr_j, mn_j, klacc,
                    nullptr, nullptr, EXXNTb, EXb, EXXTb);

  // store entry state
  *(float4*)(zscr + j*16 + 4*rgrp) = *(float4*)&VL[j][4*rgrp];
  if (rgrp == 0) zscr[256 + j] = mn_j;
  if (c == 0 && tid == 0) out[KL_OFF + b] = -out[KL_OFF + b];
}

// =====================================================================
// Pass 2b: bwd main — exact smoother over own range [c*CL, min((c+1)*CL,999)).
// Writes m_t -> EX, C_t -> EXXNT, V_t raw -> EXXT, kl partial via atomicAdd.
// =====================================================================
__global__ __launch_bounds__(64) void lds_bwd_main(
    const float* __restrict__ Jrd, const float* __restrict__ hr,
    const float* __restrict__ Lamp, const float* __restrict__ X,
    float* __restrict__ out)
{
  const int c = blockIdx.x, b = blockIdx.y;
  const int tid = threadIdx.x;
  const int j = tid & 15, rgrp = tid >> 4;

  __shared__ __align__(16) float sA[16][ST], sLp[16][ST], sLam[16][ST], sAtLT[16][ST];
  __shared__ __align__(16) float PiL[16][ST], GL[16][ST], WL[16][ST], VL[16][ST];

  float4 atltr0, atltr1, atltr2, atltr3;
  bwd_setup(Lamp, X, rgrp, j, sA, sLp, sLam, sAtLT, atltr0, atltr1, atltr2, atltr3);

  const float* JrdB = Jrd + (long long)b*TT*16;
  const float* hrB  = hr  + (long long)b*TT*16;
  float* EXXNTb = out + EXXNT_OFF + (long long)b*(TT-1)*256;
  float* EXb    = out + EX_OFF    + (long long)b*TT*16;
  float* EXXTb  = out + EXXT_OFF  + (long long)b*TT*256;
  const float* zscr = out + Z_OFF + (long long)(b*NC + c)*272;

  const int s0 = c*CL;
  const int e  = min((c+1)*CL, TT-1);

  // load entry state
  *(float4*)&VL[j][4*rgrp] = *(const float4*)(zscr + j*16 + 4*rgrp);
  float mn_j = zscr[256 + j];
  float klacc = 0.f;
  WSYNC();

  if (c == NC-1){
    // t = 999 kl term (entry state is VT, mT)
    if (rgrp == 0){
      float jr = JrdB[(TT-1)*16 + j] + 0.5f, hv = hrB[(TT-1)*16 + j];
      klacc += -0.5f*jr*(VL[j][j] + mn_j*mn_j) + hv*mn_j;
    }
  }

  // prefetch first step
  float4 pi4 = *(const float4*)(EXXNTb + (long long)(e-1)*256 + j*16 + 4*rgrp);
  float pm_j = EXb[(e-1)*16 + j];
  float jr_j = JrdB[(e-1)*16 + j], hr_j = hrB[(e-1)*16 + j];
  WSYNC();

#pragma unroll 1
  for (int t = e-1; t >= s0; --t)
    bwd_step<true>(t, s0, rgrp, j, PiL, GL, WL, VL,
                   atltr0, atltr1, atltr2, atltr3,
                   pi4, pm_j, jr_j, hr_j, mn_j, klacc,
                   JrdB, hrB, EXXNTb, EXb, EXXTb);

  klacc += __shfl_xor(klacc, 1);  klacc += __shfl_xor(klacc, 2);
  klacc += __shfl_xor(klacc, 4);  klacc += __shfl_xor(klacc, 8);
  klacc += __shfl_xor(klacc, 16); klacc += __shfl_xor(klacc, 32);
  if (tid == 0) atomicAdd(out + KL_OFF + b, klacc);
}

// =====================================================================
// Pass 3: parallel sampler prep. One wave per (b,t), t=0..998.
// =====================================================================
__global__ __launch_bounds__(64) void lds_prep(float* __restrict__ out)
{
  const int t = blockIdx.x;   // 0..998
  const int b = blockIdx.y;
  const int tid = threadIdx.x;
  const int j = tid & 15, rgrp = tid >> 4;

  __shared__ __align__(16) float CtTL[16][ST], KTL[16][ST];

  float* EXXNTb = out + EXXNT_OFF + (long long)b*(TT-1)*256;
  float* EXb    = out + EX_OFF    + (long long)b*TT*16;
  float* EXXTb  = out + EXXT_OFF  + (long long)b*TT*256;
  float* zB     = out + Z_OFF     + (long long)b*TT*16;

  float4 vt4 = *(float4*)(EXXTb + (long long)t*256 + j*16 + 4*rgrp);
  float aM[4] = {vt4.x, vt4.y, vt4.z, vt4.w};
  float aS[4];
#pragma unroll
  for (int q = 0; q < 4; ++q) aS[q] = EXXNTb[(long long)t*256 + (4*rgrp+q)*16 + j];
  *(float4*)&CtTL[j][4*rgrp] = make_float4(aS[0],aS[1],aS[2],aS[3]);
  float dummy = 0.f;
  sweep16<true,false>(aM, aS, rgrp, j, dummy);
  *(float4*)(EXXNTb + (long long)t*256 + j*16 + 4*rgrp) = make_float4(aS[0],aS[1],aS[2],aS[3]); // KT
  *(float4*)&KTL[j][4*rgrp] = make_float4(aS[0],aS[1],aS[2],aS[3]);
  WSYNC();

  float4 vn4 = *(float4*)(EXXTb + (long long)(t+1)*256 + j*16 + 4*rgrp);
  float cv[4];
#pragma unroll
  for (int q = 0; q < 4; ++q){
    int i = 4*rgrp + q;
    float4 c0 = *(float4*)&CtTL[i][0],  c1 = *(float4*)&CtTL[i][4];
    float4 c2 = *(float4*)&CtTL[i][8],  c3 = *(float4*)&CtTL[i][12];
    float4 k0 = *(float4*)&KTL[j][0],   k1 = *(float4*)&KTL[j][4];
    float4 k2 = *(float4*)&KTL[j][8],   k3 = *(float4*)&KTL[j][12];
    float s = dot4(c0,k0) + dot4(c1,k1) + dot4(c2,k2) + dot4(c3,k3);
    float vn = (q==0)?vn4.x:(q==1)?vn4.y:(q==2)?vn4.z:vn4.w;
    cv[q] = vn - s + ((i==j) ? 1e-6f : 0.f);
  }
  chol16r(cv, rgrp, j);

  unsigned kk0, kk1; batch_key(b, kk0, kk1);
  float e_j  = eps_val(kk0, kk1, (t+1)*16 + j);
  float mt_j = EXb[t*16 + j];
  float mn_j = EXb[(t+1)*16 + j];

  float pu[4];
#pragma unroll
  for (int q = 0; q < 4; ++q){
    int i = 4*rgrp + q;
    float kt = KTL[i][j];
    pu[q] = ((j <= i) ? cv[q]*e_j : 0.f) - kt*mt_j;
  }
#pragma unroll
  for (int q = 0; q < 4; ++q) pu[q] = xor16sum(pu[q]);
  float u_j = mn_j + row2col(pu[0],pu[1],pu[2],pu[3], j);
  if (rgrp == 0) zB[(t+1)*16 + j] = u_j;

  if (t == 0){
    float cv0[4] = {vt4.x, vt4.y, vt4.z, vt4.w};
#pragma unroll
    for (int q = 0; q < 4; ++q){ if (4*rgrp+q == j) cv0[q] += 1e-6f; }
    chol16r(cv0, rgrp, j);
    float e0 = eps_val(kk0, kk1, j);
    float p[4];
#pragma unroll
    for (int q = 0; q < 4; ++q){ int i = 4*rgrp + q; p[q] = (j <= i) ? cv0[q]*e0 : 0.f; }
#pragma unroll
    for (int q = 0; q < 4; ++q) p[q] = xor16sum(p[q]);
    float x0_j = mt_j + row2col(p[0],p[1],p[2],p[3], j);
    if (rgrp == 0) zB[j] = x0_j;
  }
}

// =====================================================================
// Pass 4a: chain warm — entry z at t=c*CL via warm-started recursion.
// Reads z-slots (u values, untouched here) + EX means; stores entry into d_ws.
// =====================================================================
__global__ __launch_bounds__(64) void lds_chain_warm(float* __restrict__ out,
                                                     float* __restrict__ wscr)
{
  const int c = blockIdx.x, b = blockIdx.y;
  const int tid = threadIdx.x;
  const int j = tid & 15, rgrp = tid >> 4;
  float* zB  = out + Z_OFF + (long long)b*TT*16;
  float* KTb = out + EXXNT_OFF + (long long)b*(TT-1)*256;
  const float* EXb = out + EX_OFF + (long long)b*TT*16;

  const int s0  = c * CL;
  const int t0w = max(0, s0 - WARM);
  float zj = (t0w == 0) ? zB[j] : EXb[t0w*16 + j];
  float zc0 = __shfl(zj, 4*rgrp+0), zc1 = __shfl(zj, 4*rgrp+1);
  float zc2 = __shfl(zj, 4*rgrp+2), zc3 = __shfl(zj, 4*rgrp+3);

#pragma unroll 1
  for (int t = t0w; t < s0; ++t){
    float4 k4 = *(const float4*)(KTb + (long long)t*256 + j*16 + 4*rgrp);
    float u = zB[(t+1)*16 + j];
    float p = k4.x*zc0 + k4.y*zc1 + k4.z*zc2 + k4.w*zc3;
    p += __shfl_xor(p, 16); p += __shfl_xor(p, 32);
    zj = p + u;
    zc0 = __shfl(zj, 4*rgrp+0); zc1 = __shfl(zj, 4*rgrp+1);
    zc2 = __shfl(zj, 4*rgrp+2); zc3 = __shfl(zj, 4*rgrp+3);
  }
  if (rgrp == 0) wscr[(long long)(b*NC + c)*16 + j] = zj;
}

// =====================================================================
// Pass 4b: chain main — exact z over own range, from scratch entry.
// =====================================================================
__global__ __launch_bounds__(64) void lds_chain_main(float* __restrict__ out,
                                                     const float* __restrict__ wscr)
{
  const int c = blockIdx.x, b = blockIdx.y;
  const int tid = threadIdx.x;
  const int j = tid & 15, rgrp = tid >> 4;
  float* zB  = out + Z_OFF + (long long)b*TT*16;
  float* KTb = out + EXXNT_OFF + (long long)b*(TT-1)*256;

  const int s0 = c * CL;
  const int s1 = min(s0 + CL, TT - 1);
  float zj = wscr[(long long)(b*NC + c)*16 + j];
  float zc0 = __shfl(zj, 4*rgrp+0), zc1 = __shfl(zj, 4*rgrp+1);
  float zc2 = __shfl(zj, 4*rgrp+2), zc3 = __shfl(zj, 4*rgrp+3);

#pragma unroll 1
  for (int t = s0; t < s1; ++t){
    float4 k4 = *(const float4*)(KTb + (long long)t*256 + j*16 + 4*rgrp);
    float u = zB[(t+1)*16 + j];
    float p = k4.x*zc0 + k4.y*zc1 + k4.z*zc2 + k4.w*zc3;
    p += __shfl_xor(p, 16); p += __shfl_xor(p, 32);
    float zn = p + u;
    if (rgrp == 0) zB[(t+1)*16 + j] = zn;
    zj = zn;
    zc0 = __shfl(zj, 4*rgrp+0); zc1 = __shfl(zj, 4*rgrp+1);
    zc2 = __shfl(zj, 4*rgrp+2); zc3 = __shfl(zj, 4*rgrp+3);
  }
}

// =====================================================================
// Pass 5: parallel moment finalization. One wave per (b,t), t=0..999.
// =====================================================================
__global__ __launch_bounds__(64) void lds_mom(float* __restrict__ out)
{
  const int t = blockIdx.x;   // 0..999
  const int b = blockIdx.y;
  const int tid = threadIdx.x;
  const int j = tid & 15, rgrp = tid >> 4;

  __shared__ __align__(16) float VtL[16][ST], KTL[16][ST];

  float* EXXNTb = out + EXXNT_OFF + (long long)b*(TT-1)*256;
  float* EXb    = out + EX_OFF    + (long long)b*TT*16;
  float* EXXTb  = out + EXXT_OFF  + (long long)b*TT*256;

  float4 vt4 = *(float4*)(EXXTb + (long long)t*256 + j*16 + 4*rgrp);
  float mt_j = EXb[t*16 + j];
  float mtr[4];
#pragma unroll
  for (int q = 0; q < 4; ++q) mtr[q] = EXb[t*16 + 4*rgrp + q];

  float4 f4;
  f4.x = vt4.x + mt_j*mtr[0]; f4.y = vt4.y + mt_j*mtr[1];
  f4.z = vt4.z + mt_j*mtr[2]; f4.w = vt4.w + mt_j*mtr[3];

  if (t == TT-1){
    *(float4*)(EXXTb + (long long)t*256 + j*16 + 4*rgrp) = f4;
    return;
  }
  float4 kt4 = *(float4*)(EXXNTb + (long long)t*256 + j*16 + 4*rgrp);
  *(float4*)&VtL[j][4*rgrp] = vt4;
  *(float4*)&KTL[j][4*rgrp] = kt4;
  *(float4*)(EXXTb + (long long)t*256 + j*16 + 4*rgrp) = f4;
  WSYNC();

  float mn_j = EXb[(t+1)*16 + j];
  float4 k0 = *(float4*)&KTL[j][0],  k1 = *(float4*)&KTL[j][4];
  float4 k2 = *(float4*)&KTL[j][8],  k3 = *(float4*)&KTL[j][12];
#pragma unroll
  for (int q = 0; q < 4; ++q){
    int i = 4*rgrp + q;
    float4 v0 = *(float4*)&VtL[i][0],  v1 = *(float4*)&VtL[i][4];
    float4 v2 = *(float4*)&VtL[i][8],  v3 = *(float4*)&VtL[i][12];
    float ct = dot4(v0,k0) + dot4(v1,k1) + dot4(v2,k2) + dot4(v3,k3);
    EXXNTb[(long long)t*256 + i*16 + j] = ct + mtr[q]*mn_j;
  }
}

// =====================================================================
extern "C" void kernel_launch(void* const* d_in, const int* in_sizes, int n_in,
                              void* d_out, int out_size, void* d_ws, size_t ws_size,
                              hipStream_t stream) {
  (void)in_sizes; (void)n_in; (void)ws_size; (void)out_size;
  const float* Jrd  = (const float*)d_in[0];
  const float* hr   = (const float*)d_in[1];
  const float* loc  = (const float*)d_in[2];
  const float* Taup = (const float*)d_in[3];
  const float* Lamp = (const float*)d_in[4];
  const float* X    = (const float*)d_in[5];
  float* out = (float*)d_out;
  float* ws  = (float*)d_ws;   // 64*NC*16 floats = 128 KB for chain entries

  init_kl<<<1, 64, 0, stream>>>(out);
  lds_fwd<<<dim3(NC, 64), 64, 0, stream>>>(Jrd, hr, loc, Taup, Lamp, X, out);
  lds_bwd_warm<<<dim3(NC, 64), 64, 0, stream>>>(Lamp, X, out);
  lds_bwd_main<<<dim3(NC, 64), 64, 0, stream>>>(Jrd, hr, Lamp, X, out);
  lds_prep<<<dim3(TT-1, 64), 64, 0, stream>>>(out);
  lds_chain_warm<<<dim3(NC, 64), 64, 0, stream>>>(out, ws);
  lds_chain_main<<<dim3(NC, 64), 64, 0, stream>>>(out, ws);
  lds_mom<<<dim3(TT, 64), 64, 0, stream>>>(out);
}